// Round 5
// baseline (237.039 us; speedup 1.0000x reference)
//
#include <hip/hip_runtime.h>

#define BK 32

typedef __attribute__((ext_vector_type(8))) short bf16x8;
typedef __attribute__((ext_vector_type(4))) float f32x4;

__device__ __forceinline__ unsigned short f2bf(float f) {
  unsigned u = __builtin_bit_cast(unsigned, f);
  unsigned r = (u + 0x7FFFu + ((u >> 16) & 1u)) >> 16;
  return (unsigned short)r;
}
__device__ __forceinline__ float bf2f(unsigned short h) {
  return __builtin_bit_cast(float, (unsigned)h << 16);
}
__device__ __forceinline__ unsigned pack2(unsigned short a, unsigned short b) {
  return (unsigned)a | ((unsigned)b << 16);
}

__device__ __forceinline__ void gld_lds16(const void* g, void* l) {
  __builtin_amdgcn_global_load_lds(
      (const __attribute__((address_space(1))) unsigned int*)g,
      (__attribute__((address_space(3))) unsigned int*)l, 16, 0, 0);
}

// split 8 fp32 -> hi/lo bf16, store as uint4 pair (ds_write_b128)
__device__ __forceinline__ void split8_store(float4 v0, float4 v1,
                                             unsigned short* Hdst,
                                             unsigned short* Ldst) {
  float f[8] = {v0.x, v0.y, v0.z, v0.w, v1.x, v1.y, v1.z, v1.w};
  unsigned short hh[8], ll[8];
#pragma unroll
  for (int i = 0; i < 8; ++i) {
    hh[i] = f2bf(f[i]);
    ll[i] = f2bf(f[i] - bf2f(hh[i]));
  }
  *reinterpret_cast<uint4*>(Hdst) = make_uint4(pack2(hh[0], hh[1]), pack2(hh[2], hh[3]),
                                               pack2(hh[4], hh[5]), pack2(hh[6], hh[7]));
  *reinterpret_cast<uint4*>(Ldst) = make_uint4(pack2(ll[0], ll[1]), pack2(ll[2], ll[3]),
                                               pack2(ll[4], ll[5]), pack2(ll[6], ll[7]));
}

// -------- QB prep: Th/Tl[d][k] = split-bf16 of [Qm | Km] column d --------
__global__ __launch_bounds__(256) void qkm_split(const float* __restrict__ Qm,
                                                 const float* __restrict__ Km,
                                                 unsigned short* __restrict__ Th,
                                                 unsigned short* __restrict__ Tl) {
  __shared__ float lt[64][65];
  int k0 = blockIdx.x * 64;
  int half = blockIdx.y;
  const float* M = half ? Km : Qm;
  int t = threadIdx.x;
  int cl = (t & 15) * 4;
  int rl = t >> 4;
#pragma unroll
  for (int rr = 0; rr < 4; ++rr) {
    int r = rl + rr * 16;
    float4 v = *reinterpret_cast<const float4*>(&M[(long)(k0 + r) * 64 + cl]);
    lt[cl + 0][r] = v.x;
    lt[cl + 1][r] = v.y;
    lt[cl + 2][r] = v.z;
    lt[cl + 3][r] = v.w;
  }
  __syncthreads();
#pragma unroll
  for (int rr = 0; rr < 4; ++rr) {
    int c = rl + rr * 16;
    unsigned short h[4], lo[4];
#pragma unroll
    for (int i = 0; i < 4; ++i) {
      float f = lt[c][cl + i];
      h[i] = f2bf(f);
      lo[i] = f2bf(f - bf2f(h[i]));
    }
    *reinterpret_cast<uint2*>(&Th[(long)(half * 64 + c) * 1024 + k0 + cl]) =
        make_uint2(pack2(h[0], h[1]), pack2(h[2], h[3]));
    *reinterpret_cast<uint2*>(&Tl[(long)(half * 64 + c) * 1024 + k0 + cl]) =
        make_uint2(pack2(lo[0], lo[1]), pack2(lo[2], lo[3]));
  }
}

// -------- K1: qk[32768,128] = x @ [Qm|Km], split-bf16 MFMA, dbuf pipeline --------
__global__ __launch_bounds__(256) void k1_mfma(const float* __restrict__ x,
                                               const unsigned short* __restrict__ Th,
                                               const unsigned short* __restrict__ Tl,
                                               float* __restrict__ qk) {
  __shared__ unsigned short Dh[2][128 * 32];
  __shared__ unsigned short Dl[2][128 * 32];
  __shared__ unsigned short Xh[2][64 * 32];
  __shared__ unsigned short Xl[2][64 * 32];
  const int t = threadIdx.x;
  const int l = t & 63;
  const int w = t >> 6;
  const int wr = w >> 1, wc = w & 1;
  const long mBase = (long)blockIdx.x * 64;

  f32x4 acc[4][2];
#pragma unroll
  for (int m = 0; m < 4; ++m)
#pragma unroll
    for (int n = 0; n < 2; ++n) acc[m][n] = (f32x4){0.f, 0.f, 0.f, 0.f};

  const int xrow_l = t >> 2;
  const int kslot = t & 3;
  const int xsl = kslot ^ ((t >> 3) & 3);
  const int srcslot = (l & 3) ^ ((l >> 3) & 3);
  const int frag_off = (l & 15) * 32 + ((((l >> 4) ^ (l >> 1)) & 3) * 8);
  const float* xrow = x + (mBase + xrow_l) * 1024;

#define K1_STAGE_B(k0, p)                                                     \
  {                                                                           \
    _Pragma("unroll") for (int c = 0; c < 2; ++c) {                           \
      int ch = c * 4 + w;                                                     \
      int row = ch * 16 + (l >> 2);                                           \
      gld_lds16(Th + (long)row * 1024 + (k0) + srcslot * 8, &Dh[p][ch * 512]);\
      gld_lds16(Tl + (long)row * 1024 + (k0) + srcslot * 8, &Dl[p][ch * 512]);\
    }                                                                         \
  }

#define K1_COMPUTE(p)                                                         \
  {                                                                           \
    bf16x8 dh[4], dl[4], xh[2], xl[2];                                        \
    _Pragma("unroll") for (int m = 0; m < 4; ++m) {                           \
      dh[m] = *reinterpret_cast<const bf16x8*>(&Dh[p][(wr * 64 + m * 16) * 32 + frag_off]); \
      dl[m] = *reinterpret_cast<const bf16x8*>(&Dl[p][(wr * 64 + m * 16) * 32 + frag_off]); \
    }                                                                         \
    _Pragma("unroll") for (int n = 0; n < 2; ++n) {                           \
      xh[n] = *reinterpret_cast<const bf16x8*>(&Xh[p][(wc * 32 + n * 16) * 32 + frag_off]); \
      xl[n] = *reinterpret_cast<const bf16x8*>(&Xl[p][(wc * 32 + n * 16) * 32 + frag_off]); \
    }                                                                         \
    _Pragma("unroll") for (int m = 0; m < 4; ++m)                             \
        _Pragma("unroll") for (int n = 0; n < 2; ++n) {                       \
      acc[m][n] = __builtin_amdgcn_mfma_f32_16x16x32_bf16(dh[m], xh[n], acc[m][n], 0, 0, 0); \
      acc[m][n] = __builtin_amdgcn_mfma_f32_16x16x32_bf16(dh[m], xl[n], acc[m][n], 0, 0, 0); \
      acc[m][n] = __builtin_amdgcn_mfma_f32_16x16x32_bf16(dl[m], xh[n], acc[m][n], 0, 0, 0); \
    }                                                                         \
  }

  // prologue: tile 0 into buffer 0
  {
    float4 p0 = *reinterpret_cast<const float4*>(&xrow[kslot * 8]);
    float4 p1 = *reinterpret_cast<const float4*>(&xrow[kslot * 8 + 4]);
    K1_STAGE_B(0, 0);
    split8_store(p0, p1, &Xh[0][xrow_l * 32 + xsl * 8], &Xl[0][xrow_l * 32 + xsl * 8]);
  }

  for (int k0 = 0; k0 < 1024; k0 += 64) {
    // phase 0: compute buf0 (tile k0), prefetch k0+32 into buf1
    __syncthreads();
    float4 na0 = *reinterpret_cast<const float4*>(&xrow[k0 + 32 + kslot * 8]);
    float4 na1 = *reinterpret_cast<const float4*>(&xrow[k0 + 32 + kslot * 8 + 4]);
    K1_STAGE_B(k0 + 32, 1);
    K1_COMPUTE(0);
    split8_store(na0, na1, &Xh[1][xrow_l * 32 + xsl * 8], &Xl[1][xrow_l * 32 + xsl * 8]);
    // phase 1: compute buf1 (tile k0+32), prefetch k0+64 into buf0
    __syncthreads();
    if (k0 + 64 < 1024) {
      float4 nb0 = *reinterpret_cast<const float4*>(&xrow[k0 + 64 + kslot * 8]);
      float4 nb1 = *reinterpret_cast<const float4*>(&xrow[k0 + 64 + kslot * 8 + 4]);
      K1_STAGE_B(k0 + 64, 0);
      K1_COMPUTE(1);
      split8_store(nb0, nb1, &Xh[0][xrow_l * 32 + xsl * 8], &Xl[0][xrow_l * 32 + xsl * 8]);
    } else {
      K1_COMPUTE(1);
    }
  }

#pragma unroll
  for (int m = 0; m < 4; ++m)
#pragma unroll
    for (int n = 0; n < 2; ++n) {
      int d0 = wr * 64 + m * 16 + (l >> 4) * 4;
      long xr = mBase + wc * 32 + n * 16 + (l & 15);
      *reinterpret_cast<float4*>(&qk[xr * 128 + d0]) =
          make_float4(acc[m][n][0], acc[m][n][1], acc[m][n][2], acc[m][n][3]);
    }
#undef K1_STAGE_B
#undef K1_COMPUTE
}

// -------- K2a: st[b,j,i] = exp(sigmoid(q_i . k_j)) via split-bf16 MFMA --------
__global__ __launch_bounds__(256) void k2a_mfma(const float* __restrict__ qk,
                                                unsigned short* __restrict__ st) {
  __shared__ unsigned short Ah[128 * 32];
  __shared__ unsigned short Al[128 * 32];
  __shared__ unsigned short Bh[128 * 32];
  __shared__ unsigned short Bl[128 * 32];
  const int t = threadIdx.x;
  const int l = t & 63;
  const int w = t >> 6;
  const int wr = w >> 1, wc = w & 1;

  // XCD-chunked bijective swizzle, tiles-inner b-major
  const int cpx = gridDim.x >> 3;
  const int orig = blockIdx.x;
  const int lw = (orig & 7) * cpx + (orig >> 3);
  const int b = lw >> 4;
  const int tile = lw & 15;
  const int iBase = (tile >> 2) * 128;
  const int jBase = (tile & 3) * 128;
  const float* qb = qk + (long)b * 512 * 128;

  f32x4 acc[4][4];
#pragma unroll
  for (int m = 0; m < 4; ++m)
#pragma unroll
    for (int n = 0; n < 4; ++n) acc[m][n] = (f32x4){0.f, 0.f, 0.f, 0.f};

  const int r0 = t >> 2;
  const int kslot = t & 3;
  const int sl = kslot ^ ((t >> 3) & 3);
  const int frag_off = (l & 15) * 32 + ((((l >> 4) ^ (l >> 1)) & 3) * 8);

  for (int d0 = 0; d0 < 64; d0 += BK) {
    __syncthreads();
#pragma unroll
    for (int h = 0; h < 2; ++h) {
      int row = r0 + h * 64;
      const float* qa = &qb[(long)(iBase + row) * 128 + d0 + kslot * 8];
      float4 a0 = *reinterpret_cast<const float4*>(qa);
      float4 a1 = *reinterpret_cast<const float4*>(qa + 4);
      split8_store(a0, a1, &Ah[row * 32 + sl * 8], &Al[row * 32 + sl * 8]);
      const float* kb = &qb[(long)(jBase + row) * 128 + 64 + d0 + kslot * 8];
      float4 b0 = *reinterpret_cast<const float4*>(kb);
      float4 b1 = *reinterpret_cast<const float4*>(kb + 4);
      split8_store(b0, b1, &Bh[row * 32 + sl * 8], &Bl[row * 32 + sl * 8]);
    }
    __syncthreads();

    bf16x8 ah[4], al4[4], bh[4], bl4[4];
#pragma unroll
    for (int m = 0; m < 4; ++m) {
      ah[m] = *reinterpret_cast<const bf16x8*>(&Ah[(wr * 64 + m * 16) * 32 + frag_off]);
      al4[m] = *reinterpret_cast<const bf16x8*>(&Al[(wr * 64 + m * 16) * 32 + frag_off]);
    }
#pragma unroll
    for (int n = 0; n < 4; ++n) {
      bh[n] = *reinterpret_cast<const bf16x8*>(&Bh[(wc * 64 + n * 16) * 32 + frag_off]);
      bl4[n] = *reinterpret_cast<const bf16x8*>(&Bl[(wc * 64 + n * 16) * 32 + frag_off]);
    }
#pragma unroll
    for (int m = 0; m < 4; ++m)
#pragma unroll
      for (int n = 0; n < 4; ++n) {
        acc[m][n] = __builtin_amdgcn_mfma_f32_16x16x32_bf16(ah[m], bh[n], acc[m][n], 0, 0, 0);
        acc[m][n] = __builtin_amdgcn_mfma_f32_16x16x32_bf16(ah[m], bl4[n], acc[m][n], 0, 0, 0);
        acc[m][n] = __builtin_amdgcn_mfma_f32_16x16x32_bf16(al4[m], bh[n], acc[m][n], 0, 0, 0);
      }
  }
  unsigned short* sb = st + (long)b * 512 * 512;
#pragma unroll
  for (int m = 0; m < 4; ++m)
#pragma unroll
    for (int n = 0; n < 4; ++n) {
      int i0 = iBase + wr * 64 + m * 16 + (l >> 4) * 4;
      int j = jBase + wc * 64 + n * 16 + (l & 15);
      unsigned short p[4];
#pragma unroll
      for (int reg = 0; reg < 4; ++reg) {
        float sg = 1.0f / (1.0f + __expf(-acc[m][n][reg]));
        p[reg] = f2bf(__expf(sg));
      }
      *reinterpret_cast<uint2*>(&sb[(long)j * 512 + i0]) = *reinterpret_cast<uint2*>(p);
    }
}

// -------- K2b: per-row (j) sums of st -> rsum = 1/sum, attbias = (st.bias)/sum ----
__global__ __launch_bounds__(256) void k2b_rsum(const unsigned short* __restrict__ st,
                                                const float* __restrict__ bias,
                                                float* __restrict__ rsum,
                                                float* __restrict__ attbias) {
  int jg = blockIdx.x * 4 + (threadIdx.x >> 6);
  int l = threadIdx.x & 63;
  const unsigned short* row = st + (long)jg * 512 + l * 8;
  ushort4 u0 = *reinterpret_cast<const ushort4*>(row);
  ushort4 u1 = *reinterpret_cast<const ushort4*>(row + 4);
  float4 b0 = *reinterpret_cast<const float4*>(&bias[l * 8]);
  float4 b1 = *reinterpret_cast<const float4*>(&bias[l * 8 + 4]);
  float f0 = bf2f(u0.x), f1 = bf2f(u0.y), f2 = bf2f(u0.z), f3 = bf2f(u0.w);
  float f4 = bf2f(u1.x), f5 = bf2f(u1.y), f6 = bf2f(u1.z), f7 = bf2f(u1.w);
  float sum = (f0 + f1) + (f2 + f3) + ((f4 + f5) + (f6 + f7));
  float sumb = f0 * b0.x + f1 * b0.y + f2 * b0.z + f3 * b0.w +
               f4 * b1.x + f5 * b1.y + f6 * b1.z + f7 * b1.w;
#pragma unroll
  for (int off = 32; off > 0; off >>= 1) {
    sum += __shfl_down(sum, off);
    sumb += __shfl_down(sumb, off);
  }
  if (l == 0) {
    float r = 1.0f / sum;
    rsum[jg] = r;
    attbias[jg] = sumb * r;
  }
}

// -------- transpose + fp32->bf16 convert: out[c][r] = bf16(in[r][c]) --------
__global__ __launch_bounds__(256) void transpose_conv(const float* __restrict__ in,
                                                      unsigned short* __restrict__ out,
                                                      int inRows, int inCols,
                                                      long inBatch, long outBatch) {
  __shared__ unsigned short lt[64][65];
  int b = blockIdx.z;
  int r0 = blockIdx.y * 64;
  int c0 = blockIdx.x * 64;
  const float* I = in + (long)b * inBatch;
  unsigned short* O = out + (long)b * outBatch;
  int t = threadIdx.x;
  int cl = (t & 15) * 4;
  int rl = t >> 4;
#pragma unroll
  for (int rr = 0; rr < 4; ++rr) {
    int r = rl + rr * 16;
    float4 v = *reinterpret_cast<const float4*>(&I[(long)(r0 + r) * inCols + c0 + cl]);
    lt[cl + 0][r] = f2bf(v.x);
    lt[cl + 1][r] = f2bf(v.y);
    lt[cl + 2][r] = f2bf(v.z);
    lt[cl + 3][r] = f2bf(v.w);
  }
  __syncthreads();
#pragma unroll
  for (int rr = 0; rr < 4; ++rr) {
    int c = rl + rr * 16;
    unsigned short v[4] = {lt[c][cl], lt[c][cl + 1], lt[c][cl + 2], lt[c][cl + 3]};
    *reinterpret_cast<uint2*>(&O[(long)(c0 + c) * inRows + r0 + cl]) =
        *reinterpret_cast<uint2*>(&v[0]);
  }
}

// -------- bf16 MFMA GEMM, 128x128 tile, BK=32, dbuf pipeline + XCD swizzle ------
// MODE 0 (K3): A=vwT[c][i] (unbatched), B=st[b][j][i]; weff[b,j,c] = rsum[j]*D[c][j]
// MODE 1 (K4): A=xbT[b][n][c], B=weff[b][j][c]; out[b,j,n] = D[n][j] + attbias[j]
template <int MODE>
__global__ __launch_bounds__(256) void mfma_nt(const unsigned short* __restrict__ Abase,
                                               const unsigned short* __restrict__ Bbase,
                                               const float* __restrict__ rowscale,
                                               unsigned short* __restrict__ Wout,
                                               float* __restrict__ Fout) {
  __shared__ unsigned short As[2][128 * 32];
  __shared__ unsigned short Bs[2][128 * 32];
  const int t = threadIdx.x;
  const int l = t & 63;
  const int w = t >> 6;
  const int wr = w >> 1, wc = w & 1;

  // XCD-chunked bijective swizzle; logical order: b-major, tiles inner
  const int cpx = gridDim.x >> 3;
  const int orig = blockIdx.x;
  const int lw = (orig & 7) * cpx + (orig >> 3);
  const int TPB_SH = (MODE == 0) ? 4 : 5;
  const int b = lw >> TPB_SH;
  const int tile = lw & ((1 << TPB_SH) - 1);
  const int mBase = (tile >> 2) * 128;
  const int nBase = (tile & 3) * 128;

  const unsigned short* Ag = Abase + ((MODE == 0) ? 0L : (long)b * (1024 * 512)) + (long)mBase * 512;
  const unsigned short* Bg = Bbase + (long)b * (512 * 512) + (long)nBase * 512;

  f32x4 acc[4][4];
#pragma unroll
  for (int i = 0; i < 4; ++i)
#pragma unroll
    for (int j = 0; j < 4; ++j) acc[i][j] = (f32x4){0.f, 0.f, 0.f, 0.f};

  const int srcslot = (l & 3) ^ ((l >> 3) & 3);
  const int frag_off = (l & 15) * 32 + ((((l >> 4) ^ (l >> 1)) & 3) * 8);

#define NT_STAGE(k0, p)                                                       \
  {                                                                           \
    _Pragma("unroll") for (int c = 0; c < 2; ++c) {                           \
      int ch = c * 4 + w;                                                     \
      int row = ch * 16 + (l >> 2);                                           \
      gld_lds16(Ag + (long)row * 512 + (k0) + srcslot * 8, &As[p][ch * 512]); \
      gld_lds16(Bg + (long)row * 512 + (k0) + srcslot * 8, &Bs[p][ch * 512]); \
    }                                                                         \
  }

#define NT_COMPUTE(p)                                                         \
  {                                                                           \
    bf16x8 af[4], bfr[4];                                                     \
    _Pragma("unroll") for (int m = 0; m < 4; ++m)                             \
        af[m] = *reinterpret_cast<const bf16x8*>(&As[p][(wr * 64 + m * 16) * 32 + frag_off]); \
    _Pragma("unroll") for (int n = 0; n < 4; ++n)                             \
        bfr[n] = *reinterpret_cast<const bf16x8*>(&Bs[p][(wc * 64 + n * 16) * 32 + frag_off]); \
    _Pragma("unroll") for (int m = 0; m < 4; ++m)                             \
        _Pragma("unroll") for (int n = 0; n < 4; ++n)                         \
            acc[m][n] = __builtin_amdgcn_mfma_f32_16x16x32_bf16(af[m], bfr[n], acc[m][n], 0, 0, 0); \
  }

  NT_STAGE(0, 0);
  for (int k0 = 0; k0 < 512; k0 += 64) {
    __syncthreads();
    NT_STAGE(k0 + 32, 1);
    NT_COMPUTE(0);
    __syncthreads();
    if (k0 + 64 < 512) NT_STAGE(k0 + 64, 0);
    NT_COMPUTE(1);
  }
#undef NT_STAGE
#undef NT_COMPUTE

  if (MODE == 0) {
    unsigned short* W = Wout + (long)b * (512 * 512);
#pragma unroll
    for (int m = 0; m < 4; ++m)
#pragma unroll
      for (int n = 0; n < 4; ++n) {
        int c0 = mBase + wr * 64 + m * 16 + (l >> 4) * 4;
        int j = nBase + wc * 64 + n * 16 + (l & 15);
        float rs = rowscale[b * 512 + j];
        unsigned short p[4];
#pragma unroll
        for (int reg = 0; reg < 4; ++reg) p[reg] = f2bf(acc[m][n][reg] * rs);
        *reinterpret_cast<uint2*>(&W[(long)j * 512 + c0]) = *reinterpret_cast<uint2*>(p);
      }
  } else {
    float* O = Fout + (long)b * (512 * 1024);
#pragma unroll
    for (int m = 0; m < 4; ++m)
#pragma unroll
      for (int n = 0; n < 4; ++n) {
        int n0 = mBase + wr * 64 + m * 16 + (l >> 4) * 4;
        int j = nBase + wc * 64 + n * 16 + (l & 15);
        float ab = rowscale[b * 512 + j];
        *reinterpret_cast<float4*>(&O[(long)j * 1024 + n0]) =
            make_float4(acc[m][n][0] + ab, acc[m][n][1] + ab,
                        acc[m][n][2] + ab, acc[m][n][3] + ab);
      }
  }
}

extern "C" void kernel_launch(void* const* d_in, const int* in_sizes, int n_in,
                              void* d_out, int out_size, void* d_ws, size_t ws_size,
                              hipStream_t stream) {
  const float* x  = (const float*)d_in[0];
  const float* Qm = (const float*)d_in[1];
  const float* Km = (const float*)d_in[2];
  const float* vw = (const float*)d_in[3];
  const float* vb = (const float*)d_in[4];
  float* out = (float*)d_out;

  float* ws = (float*)d_ws;
  float* qk = ws;                                                     // 4,194,304 f
  unsigned short* st   = (unsigned short*)(ws + 4194304);             // spans 8,388,608 f
  unsigned short* weff = (unsigned short*)(ws + 4194304 + 8388608);   // spans 8,388,608 f
  unsigned short* xbT  = (unsigned short*)(ws + 4194304 + 16777216);  // spans 16,777,216 f
  unsigned short* vwT  = (unsigned short*)(ws + 4194304 + 33554432);  // spans 131,072 f
  unsigned short* qkTh = (unsigned short*)(ws + 4194304 + 33554432 + 131072);  // 65,536 f
  unsigned short* qkTl = qkTh + 131072;                               // 65,536 f
  float* rsum    = ws + 4194304 + 33554432 + 131072 + 131072;         // 32,768 f
  float* attbias = rsum + 32768;                                      // 32,768 f

  // T1: xbT[b][n][c] = bf16(x[b][c][n])
  transpose_conv<<<dim3(16, 8, 64), 256, 0, stream>>>(x, xbT, 512, 1024, 524288L, 524288L);
  // T2: vwT[c][i] = bf16(vw[i][c])
  transpose_conv<<<dim3(8, 8, 1), 256, 0, stream>>>(vw, vwT, 512, 512, 0L, 0L);
  // T3: split-transposed [Qm|Km] -> qkTh/qkTl [128][1024]
  qkm_split<<<dim3(16, 2), 256, 0, stream>>>(Qm, Km, qkTh, qkTl);
  // K1: qk = x @ [Qm|Km], split-bf16 MFMA (dbuf pipeline)
  k1_mfma<<<512, 256, 0, stream>>>(x, qkTh, qkTl, qk);
  // K2a: st[b,j,i] = exp(sigmoid(q_i . k_j)), split-bf16 MFMA (XCD swizzle)
  k2a_mfma<<<1024, 256, 0, stream>>>(qk, st);
  // K2b: rsum, attbias
  k2b_rsum<<<8192, 256, 0, stream>>>(st, vb, rsum, attbias);
  // K3: weff = diag(rsum) . st . Vw   (A=vwT, B=st)
  mfma_nt<0><<<1024, 256, 0, stream>>>(vwT, st, rsum, weff, nullptr);
  // K4: out = weff . xf + attbias     (A=xbT, B=weff)
  mfma_nt<1><<<2048, 256, 0, stream>>>(xbT, weff, attbias, nullptr, out);
}

// Round 6
// 225.604 us; speedup vs baseline: 1.0507x; 1.0507x over previous
//
#include <hip/hip_runtime.h>

#define BK 32

typedef __attribute__((ext_vector_type(8))) short bf16x8;
typedef __attribute__((ext_vector_type(4))) float f32x4;

__device__ __forceinline__ unsigned short f2bf(float f) {
  unsigned u = __builtin_bit_cast(unsigned, f);
  unsigned r = (u + 0x7FFFu + ((u >> 16) & 1u)) >> 16;
  return (unsigned short)r;
}
__device__ __forceinline__ float bf2f(unsigned short h) {
  return __builtin_bit_cast(float, (unsigned)h << 16);
}
__device__ __forceinline__ unsigned pack2(unsigned short a, unsigned short b) {
  return (unsigned)a | ((unsigned)b << 16);
}

__device__ __forceinline__ void gld_lds16(const void* g, void* l) {
  __builtin_amdgcn_global_load_lds(
      (const __attribute__((address_space(1))) unsigned int*)g,
      (__attribute__((address_space(3))) unsigned int*)l, 16, 0, 0);
}

// split 8 fp32 -> hi/lo bf16, store as uint4 pair (ds_write_b128)
__device__ __forceinline__ void split8_store(float4 v0, float4 v1,
                                             unsigned short* Hdst,
                                             unsigned short* Ldst) {
  float f[8] = {v0.x, v0.y, v0.z, v0.w, v1.x, v1.y, v1.z, v1.w};
  unsigned short hh[8], ll[8];
#pragma unroll
  for (int i = 0; i < 8; ++i) {
    hh[i] = f2bf(f[i]);
    ll[i] = f2bf(f[i] - bf2f(hh[i]));
  }
  *reinterpret_cast<uint4*>(Hdst) = make_uint4(pack2(hh[0], hh[1]), pack2(hh[2], hh[3]),
                                               pack2(hh[4], hh[5]), pack2(hh[6], hh[7]));
  *reinterpret_cast<uint4*>(Ldst) = make_uint4(pack2(ll[0], ll[1]), pack2(ll[2], ll[3]),
                                               pack2(ll[4], ll[5]), pack2(ll[6], ll[7]));
}

// -------- QB prep: Th/Tl[d][k] = split-bf16 of [Qm | Km] column d --------
__global__ __launch_bounds__(256) void qkm_split(const float* __restrict__ Qm,
                                                 const float* __restrict__ Km,
                                                 unsigned short* __restrict__ Th,
                                                 unsigned short* __restrict__ Tl) {
  __shared__ float lt[64][65];
  int k0 = blockIdx.x * 64;
  int half = blockIdx.y;
  const float* M = half ? Km : Qm;
  int t = threadIdx.x;
  int cl = (t & 15) * 4;
  int rl = t >> 4;
#pragma unroll
  for (int rr = 0; rr < 4; ++rr) {
    int r = rl + rr * 16;
    float4 v = *reinterpret_cast<const float4*>(&M[(long)(k0 + r) * 64 + cl]);
    lt[cl + 0][r] = v.x;
    lt[cl + 1][r] = v.y;
    lt[cl + 2][r] = v.z;
    lt[cl + 3][r] = v.w;
  }
  __syncthreads();
#pragma unroll
  for (int rr = 0; rr < 4; ++rr) {
    int c = rl + rr * 16;
    unsigned short h[4], lo[4];
#pragma unroll
    for (int i = 0; i < 4; ++i) {
      float f = lt[c][cl + i];
      h[i] = f2bf(f);
      lo[i] = f2bf(f - bf2f(h[i]));
    }
    *reinterpret_cast<uint2*>(&Th[(long)(half * 64 + c) * 1024 + k0 + cl]) =
        make_uint2(pack2(h[0], h[1]), pack2(h[2], h[3]));
    *reinterpret_cast<uint2*>(&Tl[(long)(half * 64 + c) * 1024 + k0 + cl]) =
        make_uint2(pack2(lo[0], lo[1]), pack2(lo[2], lo[3]));
  }
}

// -------- K1: qk[32768,128] = x @ [Qm|Km], split-bf16 MFMA, dbuf pipeline --------
__global__ __launch_bounds__(256) void k1_mfma(const float* __restrict__ x,
                                               const unsigned short* __restrict__ Th,
                                               const unsigned short* __restrict__ Tl,
                                               float* __restrict__ qk) {
  __shared__ unsigned short Dh[2][128 * 32];
  __shared__ unsigned short Dl[2][128 * 32];
  __shared__ unsigned short Xh[2][64 * 32];
  __shared__ unsigned short Xl[2][64 * 32];
  const int t = threadIdx.x;
  const int l = t & 63;
  const int w = t >> 6;
  const int wr = w >> 1, wc = w & 1;
  const long mBase = (long)blockIdx.x * 64;

  f32x4 acc[4][2];
#pragma unroll
  for (int m = 0; m < 4; ++m)
#pragma unroll
    for (int n = 0; n < 2; ++n) acc[m][n] = (f32x4){0.f, 0.f, 0.f, 0.f};

  const int xrow_l = t >> 2;
  const int kslot = t & 3;
  const int xsl = kslot ^ ((t >> 3) & 3);
  const int srcslot = (l & 3) ^ ((l >> 3) & 3);
  const int frag_off = (l & 15) * 32 + ((((l >> 4) ^ (l >> 1)) & 3) * 8);
  const float* xrow = x + (mBase + xrow_l) * 1024;

#define K1_STAGE_B(k0, p)                                                     \
  {                                                                           \
    _Pragma("unroll") for (int c = 0; c < 2; ++c) {                           \
      int ch = c * 4 + w;                                                     \
      int row = ch * 16 + (l >> 2);                                           \
      gld_lds16(Th + (long)row * 1024 + (k0) + srcslot * 8, &Dh[p][ch * 512]);\
      gld_lds16(Tl + (long)row * 1024 + (k0) + srcslot * 8, &Dl[p][ch * 512]);\
    }                                                                         \
  }

#define K1_COMPUTE(p)                                                         \
  {                                                                           \
    bf16x8 dh[4], dl[4], xh[2], xl[2];                                        \
    _Pragma("unroll") for (int m = 0; m < 4; ++m) {                           \
      dh[m] = *reinterpret_cast<const bf16x8*>(&Dh[p][(wr * 64 + m * 16) * 32 + frag_off]); \
      dl[m] = *reinterpret_cast<const bf16x8*>(&Dl[p][(wr * 64 + m * 16) * 32 + frag_off]); \
    }                                                                         \
    _Pragma("unroll") for (int n = 0; n < 2; ++n) {                           \
      xh[n] = *reinterpret_cast<const bf16x8*>(&Xh[p][(wc * 32 + n * 16) * 32 + frag_off]); \
      xl[n] = *reinterpret_cast<const bf16x8*>(&Xl[p][(wc * 32 + n * 16) * 32 + frag_off]); \
    }                                                                         \
    _Pragma("unroll") for (int m = 0; m < 4; ++m)                             \
        _Pragma("unroll") for (int n = 0; n < 2; ++n) {                       \
      acc[m][n] = __builtin_amdgcn_mfma_f32_16x16x32_bf16(dh[m], xh[n], acc[m][n], 0, 0, 0); \
      acc[m][n] = __builtin_amdgcn_mfma_f32_16x16x32_bf16(dh[m], xl[n], acc[m][n], 0, 0, 0); \
      acc[m][n] = __builtin_amdgcn_mfma_f32_16x16x32_bf16(dl[m], xh[n], acc[m][n], 0, 0, 0); \
    }                                                                         \
  }

  {
    float4 p0 = *reinterpret_cast<const float4*>(&xrow[kslot * 8]);
    float4 p1 = *reinterpret_cast<const float4*>(&xrow[kslot * 8 + 4]);
    K1_STAGE_B(0, 0);
    split8_store(p0, p1, &Xh[0][xrow_l * 32 + xsl * 8], &Xl[0][xrow_l * 32 + xsl * 8]);
  }

  for (int k0 = 0; k0 < 1024; k0 += 64) {
    __syncthreads();
    float4 na0 = *reinterpret_cast<const float4*>(&xrow[k0 + 32 + kslot * 8]);
    float4 na1 = *reinterpret_cast<const float4*>(&xrow[k0 + 32 + kslot * 8 + 4]);
    K1_STAGE_B(k0 + 32, 1);
    K1_COMPUTE(0);
    split8_store(na0, na1, &Xh[1][xrow_l * 32 + xsl * 8], &Xl[1][xrow_l * 32 + xsl * 8]);
    __syncthreads();
    if (k0 + 64 < 1024) {
      float4 nb0 = *reinterpret_cast<const float4*>(&xrow[k0 + 64 + kslot * 8]);
      float4 nb1 = *reinterpret_cast<const float4*>(&xrow[k0 + 64 + kslot * 8 + 4]);
      K1_STAGE_B(k0 + 64, 0);
      K1_COMPUTE(1);
      split8_store(nb0, nb1, &Xh[0][xrow_l * 32 + xsl * 8], &Xl[0][xrow_l * 32 + xsl * 8]);
    } else {
      K1_COMPUTE(1);
    }
  }

#pragma unroll
  for (int m = 0; m < 4; ++m)
#pragma unroll
    for (int n = 0; n < 2; ++n) {
      int d0 = wr * 64 + m * 16 + (l >> 4) * 4;
      long xr = mBase + wc * 32 + n * 16 + (l & 15);
      *reinterpret_cast<float4*>(&qk[xr * 128 + d0]) =
          make_float4(acc[m][n][0], acc[m][n][1], acc[m][n][2], acc[m][n][3]);
    }
#undef K1_STAGE_B
#undef K1_COMPUTE
}

// -------- K2a: st[b,j,i] = exp(sigmoid(q_i . k_j)) via split-bf16 MFMA --------
__global__ __launch_bounds__(256) void k2a_mfma(const float* __restrict__ qk,
                                                unsigned short* __restrict__ st) {
  __shared__ unsigned short Ah[128 * 32];
  __shared__ unsigned short Al[128 * 32];
  __shared__ unsigned short Bh[128 * 32];
  __shared__ unsigned short Bl[128 * 32];
  const int t = threadIdx.x;
  const int l = t & 63;
  const int w = t >> 6;
  const int wr = w >> 1, wc = w & 1;

  const int cpx = gridDim.x >> 3;
  const int orig = blockIdx.x;
  const int lw = (orig & 7) * cpx + (orig >> 3);
  const int b = lw >> 4;
  const int tile = lw & 15;
  const int iBase = (tile >> 2) * 128;
  const int jBase = (tile & 3) * 128;
  const float* qb = qk + (long)b * 512 * 128;

  f32x4 acc[4][4];
#pragma unroll
  for (int m = 0; m < 4; ++m)
#pragma unroll
    for (int n = 0; n < 4; ++n) acc[m][n] = (f32x4){0.f, 0.f, 0.f, 0.f};

  const int r0 = t >> 2;
  const int kslot = t & 3;
  const int sl = kslot ^ ((t >> 3) & 3);
  const int frag_off = (l & 15) * 32 + ((((l >> 4) ^ (l >> 1)) & 3) * 8);

  for (int d0 = 0; d0 < 64; d0 += BK) {
    __syncthreads();
#pragma unroll
    for (int h = 0; h < 2; ++h) {
      int row = r0 + h * 64;
      const float* qa = &qb[(long)(iBase + row) * 128 + d0 + kslot * 8];
      float4 a0 = *reinterpret_cast<const float4*>(qa);
      float4 a1 = *reinterpret_cast<const float4*>(qa + 4);
      split8_store(a0, a1, &Ah[row * 32 + sl * 8], &Al[row * 32 + sl * 8]);
      const float* kb = &qb[(long)(jBase + row) * 128 + 64 + d0 + kslot * 8];
      float4 b0 = *reinterpret_cast<const float4*>(kb);
      float4 b1 = *reinterpret_cast<const float4*>(kb + 4);
      split8_store(b0, b1, &Bh[row * 32 + sl * 8], &Bl[row * 32 + sl * 8]);
    }
    __syncthreads();

    bf16x8 ah[4], al4[4], bh[4], bl4[4];
#pragma unroll
    for (int m = 0; m < 4; ++m) {
      ah[m] = *reinterpret_cast<const bf16x8*>(&Ah[(wr * 64 + m * 16) * 32 + frag_off]);
      al4[m] = *reinterpret_cast<const bf16x8*>(&Al[(wr * 64 + m * 16) * 32 + frag_off]);
    }
#pragma unroll
    for (int n = 0; n < 4; ++n) {
      bh[n] = *reinterpret_cast<const bf16x8*>(&Bh[(wc * 64 + n * 16) * 32 + frag_off]);
      bl4[n] = *reinterpret_cast<const bf16x8*>(&Bl[(wc * 64 + n * 16) * 32 + frag_off]);
    }
#pragma unroll
    for (int m = 0; m < 4; ++m)
#pragma unroll
      for (int n = 0; n < 4; ++n) {
        acc[m][n] = __builtin_amdgcn_mfma_f32_16x16x32_bf16(ah[m], bh[n], acc[m][n], 0, 0, 0);
        acc[m][n] = __builtin_amdgcn_mfma_f32_16x16x32_bf16(ah[m], bl4[n], acc[m][n], 0, 0, 0);
        acc[m][n] = __builtin_amdgcn_mfma_f32_16x16x32_bf16(al4[m], bh[n], acc[m][n], 0, 0, 0);
      }
  }
  unsigned short* sb = st + (long)b * 512 * 512;
#pragma unroll
  for (int m = 0; m < 4; ++m)
#pragma unroll
    for (int n = 0; n < 4; ++n) {
      int i0 = iBase + wr * 64 + m * 16 + (l >> 4) * 4;
      int j = jBase + wc * 64 + n * 16 + (l & 15);
      unsigned short p[4];
#pragma unroll
      for (int reg = 0; reg < 4; ++reg) {
        float sg = 1.0f / (1.0f + __expf(-acc[m][n][reg]));
        p[reg] = f2bf(__expf(sg));
      }
      *reinterpret_cast<uint2*>(&sb[(long)j * 512 + i0]) = *reinterpret_cast<uint2*>(p);
    }
}

// -------- K2b: per-row (j) sums of st -> rsum = 1/sum, attbias = (st.bias)/sum ----
__global__ __launch_bounds__(256) void k2b_rsum(const unsigned short* __restrict__ st,
                                                const float* __restrict__ bias,
                                                float* __restrict__ rsum,
                                                float* __restrict__ attbias) {
  int jg = blockIdx.x * 4 + (threadIdx.x >> 6);
  int l = threadIdx.x & 63;
  const unsigned short* row = st + (long)jg * 512 + l * 8;
  ushort4 u0 = *reinterpret_cast<const ushort4*>(row);
  ushort4 u1 = *reinterpret_cast<const ushort4*>(row + 4);
  float4 b0 = *reinterpret_cast<const float4*>(&bias[l * 8]);
  float4 b1 = *reinterpret_cast<const float4*>(&bias[l * 8 + 4]);
  float f0 = bf2f(u0.x), f1 = bf2f(u0.y), f2 = bf2f(u0.z), f3 = bf2f(u0.w);
  float f4 = bf2f(u1.x), f5 = bf2f(u1.y), f6 = bf2f(u1.z), f7 = bf2f(u1.w);
  float sum = (f0 + f1) + (f2 + f3) + ((f4 + f5) + (f6 + f7));
  float sumb = f0 * b0.x + f1 * b0.y + f2 * b0.z + f3 * b0.w +
               f4 * b1.x + f5 * b1.y + f6 * b1.z + f7 * b1.w;
#pragma unroll
  for (int off = 32; off > 0; off >>= 1) {
    sum += __shfl_down(sum, off);
    sumb += __shfl_down(sumb, off);
  }
  if (l == 0) {
    float r = 1.0f / sum;
    rsum[jg] = r;
    attbias[jg] = sumb * r;
  }
}

// -------- transpose + fp32->bf16 convert: out[c][r] = bf16(in[r][c]) --------
__global__ __launch_bounds__(256) void transpose_conv(const float* __restrict__ in,
                                                      unsigned short* __restrict__ out,
                                                      int inRows, int inCols,
                                                      long inBatch, long outBatch) {
  __shared__ unsigned short lt[64][65];
  int b = blockIdx.z;
  int r0 = blockIdx.y * 64;
  int c0 = blockIdx.x * 64;
  const float* I = in + (long)b * inBatch;
  unsigned short* O = out + (long)b * outBatch;
  int t = threadIdx.x;
  int cl = (t & 15) * 4;
  int rl = t >> 4;
#pragma unroll
  for (int rr = 0; rr < 4; ++rr) {
    int r = rl + rr * 16;
    float4 v = *reinterpret_cast<const float4*>(&I[(long)(r0 + r) * inCols + c0 + cl]);
    lt[cl + 0][r] = f2bf(v.x);
    lt[cl + 1][r] = f2bf(v.y);
    lt[cl + 2][r] = f2bf(v.z);
    lt[cl + 3][r] = f2bf(v.w);
  }
  __syncthreads();
#pragma unroll
  for (int rr = 0; rr < 4; ++rr) {
    int c = rl + rr * 16;
    unsigned short v[4] = {lt[c][cl], lt[c][cl + 1], lt[c][cl + 2], lt[c][cl + 3]};
    *reinterpret_cast<uint2*>(&O[(long)(c0 + c) * inRows + r0 + cl]) =
        *reinterpret_cast<uint2*>(&v[0]);
  }
}

// ======== 256x256-tile bf16 MFMA GEMM, BK=64, 512 thr / 8 waves (2M x 4N) ========
// One barrier per K-tile: stage next tile into buf^1 while computing buf.
// LDS 128 KiB (A 2x32K + B 2x32K). Slot swizzle: lds_slot = g_slot ^ (row & 7).
// MODE 0 (K3): A=vwT[c][i], B=st[b][j][i];  weff[b,j,c] = rsum[j] * D  (bf16)
// MODE 1 (K4): A=xbT[b][n][c], B=weff[b][j][c]; out[b,j,n] = D + attbias[j] (f32)
template <int MODE>
__global__ __launch_bounds__(512) void mfma_nt256(const unsigned short* __restrict__ Abase,
                                                  const unsigned short* __restrict__ Bbase,
                                                  const float* __restrict__ rowscale,
                                                  unsigned short* __restrict__ Wout,
                                                  float* __restrict__ Fout) {
  __shared__ unsigned short As[2][256 * 64];
  __shared__ unsigned short Bs[2][256 * 64];
  const int t = threadIdx.x;
  const int l = t & 63;
  const int w = t >> 6;          // 0..7
  const int wr = w >> 2;         // 0..1  (M: 2 x 128)
  const int wc = w & 3;          // 0..3  (N: 4 x 64)

  // XCD-chunked bijective swizzle; logical order: b-major, tiles inner
  const int cpx = gridDim.x >> 3;
  const int orig = blockIdx.x;
  const int lw = (orig & 7) * cpx + (orig >> 3);
  const int TPB_SH = (MODE == 0) ? 2 : 3;   // tiles per b: K3 2x1... (2m x 2n)=4? see below
  // K3: M=512 -> 2 mTiles, N=512 -> 2 nTiles => 4 tiles/b (TPB_SH=2)
  // K4: M=1024 -> 4 mTiles, N=512 -> 2 nTiles => 8 tiles/b (TPB_SH=3)
  const int b = lw >> TPB_SH;
  const int tile = lw & ((1 << TPB_SH) - 1);
  const int mBase = (tile >> 1) * 256;
  const int nBase = (tile & 1) * 256;

  const unsigned short* Ag = Abase + ((MODE == 0) ? 0L : (long)b * (1024 * 512)) + (long)mBase * 512;
  const unsigned short* Bg = Bbase + (long)b * (512 * 512) + (long)nBase * 512;

  f32x4 acc[8][4];
#pragma unroll
  for (int m = 0; m < 8; ++m)
#pragma unroll
    for (int n = 0; n < 4; ++n) acc[m][n] = (f32x4){0.f, 0.f, 0.f, 0.f};

  // staging: lane l -> row (+ l>>3), lds slot l&7, global slot (l&7)^(l>>3)
  const int srcslot = (l & 7) ^ (l >> 3);

#define NT_STAGE(kt, p)                                                        \
  {                                                                            \
    _Pragma("unroll") for (int pr = 0; pr < 4; ++pr) {                         \
      int rr = pr * 64 + w * 8 + (l >> 3);                                     \
      gld_lds16(Ag + (long)rr * 512 + (kt) * 64 + srcslot * 8,                 \
                &As[p][(pr * 64 + w * 8) * 64]);                               \
      gld_lds16(Bg + (long)rr * 512 + (kt) * 64 + srcslot * 8,                 \
                &Bs[p][(pr * 64 + w * 8) * 64]);                               \
    }                                                                          \
  }

#define NT_COMPUTE(p)                                                          \
  {                                                                            \
    _Pragma("unroll") for (int kk = 0; kk < 2; ++kk) {                         \
      const int so = ((kk * 4 + (l >> 4)) ^ (l & 7)) * 8;                      \
      bf16x8 af[8], bfr[4];                                                    \
      _Pragma("unroll") for (int m = 0; m < 8; ++m)                            \
        af[m] = *reinterpret_cast<const bf16x8*>(                              \
            &As[p][(wr * 128 + m * 16 + (l & 15)) * 64 + so]);                 \
      _Pragma("unroll") for (int n = 0; n < 4; ++n)                            \
        bfr[n] = *reinterpret_cast<const bf16x8*>(                             \
            &Bs[p][(wc * 64 + n * 16 + (l & 15)) * 64 + so]);                  \
      _Pragma("unroll") for (int m = 0; m < 8; ++m)                            \
        _Pragma("unroll") for (int n = 0; n < 4; ++n)                          \
          acc[m][n] = __builtin_amdgcn_mfma_f32_16x16x32_bf16(af[m], bfr[n],   \
                                                              acc[m][n], 0, 0, 0); \
    }                                                                          \
  }

  // K = 512 -> 8 K-tiles of 64
  NT_STAGE(0, 0);
  __syncthreads();
  for (int kt = 0; kt < 6; kt += 2) {
    NT_STAGE(kt + 1, 1);
    NT_COMPUTE(0);
    __syncthreads();
    NT_STAGE(kt + 2, 0);
    NT_COMPUTE(1);
    __syncthreads();
  }
  NT_STAGE(7, 1);
  NT_COMPUTE(0);
  __syncthreads();
  NT_COMPUTE(1);
#undef NT_STAGE
#undef NT_COMPUTE

  if (MODE == 0) {
    unsigned short* W = Wout + (long)b * (512 * 512);
#pragma unroll
    for (int n = 0; n < 4; ++n) {
      int j = nBase + wc * 64 + n * 16 + (l & 15);
      float rs = rowscale[b * 512 + j];
#pragma unroll
      for (int m = 0; m < 8; ++m) {
        int c0 = mBase + wr * 128 + m * 16 + (l >> 4) * 4;
        unsigned short p[4];
#pragma unroll
        for (int reg = 0; reg < 4; ++reg) p[reg] = f2bf(acc[m][n][reg] * rs);
        *reinterpret_cast<uint2*>(&W[(long)j * 512 + c0]) = *reinterpret_cast<uint2*>(p);
      }
    }
  } else {
    float* O = Fout + (long)b * (512 * 1024);
#pragma unroll
    for (int n = 0; n < 4; ++n) {
      int j = nBase + wc * 64 + n * 16 + (l & 15);
      float ab = rowscale[b * 512 + j];
#pragma unroll
      for (int m = 0; m < 8; ++m) {
        int n0 = mBase + wr * 128 + m * 16 + (l >> 4) * 4;
        *reinterpret_cast<float4*>(&O[(long)j * 1024 + n0]) =
            make_float4(acc[m][n][0] + ab, acc[m][n][1] + ab,
                        acc[m][n][2] + ab, acc[m][n][3] + ab);
      }
    }
  }
}

extern "C" void kernel_launch(void* const* d_in, const int* in_sizes, int n_in,
                              void* d_out, int out_size, void* d_ws, size_t ws_size,
                              hipStream_t stream) {
  const float* x  = (const float*)d_in[0];
  const float* Qm = (const float*)d_in[1];
  const float* Km = (const float*)d_in[2];
  const float* vw = (const float*)d_in[3];
  const float* vb = (const float*)d_in[4];
  float* out = (float*)d_out;

  float* ws = (float*)d_ws;
  float* qk = ws;                                                     // 4,194,304 f
  unsigned short* st   = (unsigned short*)(ws + 4194304);             // spans 8,388,608 f
  unsigned short* weff = (unsigned short*)(ws + 4194304 + 8388608);   // spans 8,388,608 f
  unsigned short* xbT  = (unsigned short*)(ws + 4194304 + 16777216);  // spans 16,777,216 f
  unsigned short* vwT  = (unsigned short*)(ws + 4194304 + 33554432);  // spans 131,072 f
  unsigned short* qkTh = (unsigned short*)(ws + 4194304 + 33554432 + 131072);  // 65,536 f
  unsigned short* qkTl = qkTh + 131072;                               // 65,536 f
  float* rsum    = ws + 4194304 + 33554432 + 131072 + 131072;         // 32,768 f
  float* attbias = rsum + 32768;                                      // 32,768 f

  // T1: xbT[b][n][c] = bf16(x[b][c][n])
  transpose_conv<<<dim3(16, 8, 64), 256, 0, stream>>>(x, xbT, 512, 1024, 524288L, 524288L);
  // T2: vwT[c][i] = bf16(vw[i][c])
  transpose_conv<<<dim3(8, 8, 1), 256, 0, stream>>>(vw, vwT, 512, 512, 0L, 0L);
  // T3: split-transposed [Qm|Km] -> qkTh/qkTl [128][1024]
  qkm_split<<<dim3(16, 2), 256, 0, stream>>>(Qm, Km, qkTh, qkTl);
  // K1: qk = x @ [Qm|Km], split-bf16 MFMA (dbuf pipeline)
  k1_mfma<<<512, 256, 0, stream>>>(x, qkTh, qkTl, qk);
  // K2a: st[b,j,i] = exp(sigmoid(q_i . k_j)), split-bf16 MFMA (XCD swizzle)
  k2a_mfma<<<1024, 256, 0, stream>>>(qk, st);
  // K2b: rsum, attbias
  k2b_rsum<<<8192, 256, 0, stream>>>(st, vb, rsum, attbias);
  // K3: weff = diag(rsum) . st . Vw   (A=vwT, B=st), 256^2 tiles: 4 tiles/b
  mfma_nt256<0><<<256, 512, 0, stream>>>(vwT, st, rsum, weff, nullptr);
  // K4: out = weff . xf + attbias     (A=xbT, B=weff), 8 tiles/b
  mfma_nt256<1><<<512, 512, 0, stream>>>(xbT, weff, attbias, nullptr, out);
}

// Round 7
// 221.446 us; speedup vs baseline: 1.0704x; 1.0188x over previous
//
#include <hip/hip_runtime.h>

#define BK 32

typedef __attribute__((ext_vector_type(8))) short bf16x8;
typedef __attribute__((ext_vector_type(4))) float f32x4;

__device__ __forceinline__ unsigned short f2bf(float f) {
  unsigned u = __builtin_bit_cast(unsigned, f);
  unsigned r = (u + 0x7FFFu + ((u >> 16) & 1u)) >> 16;
  return (unsigned short)r;
}
__device__ __forceinline__ float bf2f(unsigned short h) {
  return __builtin_bit_cast(float, (unsigned)h << 16);
}
__device__ __forceinline__ unsigned pack2(unsigned short a, unsigned short b) {
  return (unsigned)a | ((unsigned)b << 16);
}

__device__ __forceinline__ void gld_lds16(const void* g, void* l) {
  __builtin_amdgcn_global_load_lds(
      (const __attribute__((address_space(1))) unsigned int*)g,
      (__attribute__((address_space(3))) unsigned int*)l, 16, 0, 0);
}

#define SCHED0() __builtin_amdgcn_sched_barrier(0)
#define NTBAR() do { SCHED0(); __builtin_amdgcn_s_barrier(); SCHED0(); } while (0)
#define VMW(N) do { asm volatile("s_waitcnt vmcnt(" #N ")" ::: "memory"); SCHED0(); } while (0)

// split 8 fp32 -> hi/lo bf16, store as uint4 pair (ds_write_b128)
__device__ __forceinline__ void split8_store(float4 v0, float4 v1,
                                             unsigned short* Hdst,
                                             unsigned short* Ldst) {
  float f[8] = {v0.x, v0.y, v0.z, v0.w, v1.x, v1.y, v1.z, v1.w};
  unsigned short hh[8], ll[8];
#pragma unroll
  for (int i = 0; i < 8; ++i) {
    hh[i] = f2bf(f[i]);
    ll[i] = f2bf(f[i] - bf2f(hh[i]));
  }
  *reinterpret_cast<uint4*>(Hdst) = make_uint4(pack2(hh[0], hh[1]), pack2(hh[2], hh[3]),
                                               pack2(hh[4], hh[5]), pack2(hh[6], hh[7]));
  *reinterpret_cast<uint4*>(Ldst) = make_uint4(pack2(ll[0], ll[1]), pack2(ll[2], ll[3]),
                                               pack2(ll[4], ll[5]), pack2(ll[6], ll[7]));
}

// -------- QB prep: Th/Tl[d][k] = split-bf16 of [Qm | Km] column d --------
__global__ __launch_bounds__(256) void qkm_split(const float* __restrict__ Qm,
                                                 const float* __restrict__ Km,
                                                 unsigned short* __restrict__ Th,
                                                 unsigned short* __restrict__ Tl) {
  __shared__ float lt[64][65];
  int k0 = blockIdx.x * 64;
  int half = blockIdx.y;
  const float* M = half ? Km : Qm;
  int t = threadIdx.x;
  int cl = (t & 15) * 4;
  int rl = t >> 4;
#pragma unroll
  for (int rr = 0; rr < 4; ++rr) {
    int r = rl + rr * 16;
    float4 v = *reinterpret_cast<const float4*>(&M[(long)(k0 + r) * 64 + cl]);
    lt[cl + 0][r] = v.x;
    lt[cl + 1][r] = v.y;
    lt[cl + 2][r] = v.z;
    lt[cl + 3][r] = v.w;
  }
  __syncthreads();
#pragma unroll
  for (int rr = 0; rr < 4; ++rr) {
    int c = rl + rr * 16;
    unsigned short h[4], lo[4];
#pragma unroll
    for (int i = 0; i < 4; ++i) {
      float f = lt[c][cl + i];
      h[i] = f2bf(f);
      lo[i] = f2bf(f - bf2f(h[i]));
    }
    *reinterpret_cast<uint2*>(&Th[(long)(half * 64 + c) * 1024 + k0 + cl]) =
        make_uint2(pack2(h[0], h[1]), pack2(h[2], h[3]));
    *reinterpret_cast<uint2*>(&Tl[(long)(half * 64 + c) * 1024 + k0 + cl]) =
        make_uint2(pack2(lo[0], lo[1]), pack2(lo[2], lo[3]));
  }
}

// -------- K1: qk[32768,128] = x @ [Qm|Km], split-bf16 MFMA, dbuf pipeline --------
__global__ __launch_bounds__(256) void k1_mfma(const float* __restrict__ x,
                                               const unsigned short* __restrict__ Th,
                                               const unsigned short* __restrict__ Tl,
                                               float* __restrict__ qk) {
  __shared__ unsigned short Dh[2][128 * 32];
  __shared__ unsigned short Dl[2][128 * 32];
  __shared__ unsigned short Xh[2][64 * 32];
  __shared__ unsigned short Xl[2][64 * 32];
  const int t = threadIdx.x;
  const int l = t & 63;
  const int w = t >> 6;
  const int wr = w >> 1, wc = w & 1;
  const long mBase = (long)blockIdx.x * 64;

  f32x4 acc[4][2];
#pragma unroll
  for (int m = 0; m < 4; ++m)
#pragma unroll
    for (int n = 0; n < 2; ++n) acc[m][n] = (f32x4){0.f, 0.f, 0.f, 0.f};

  const int xrow_l = t >> 2;
  const int kslot = t & 3;
  const int xsl = kslot ^ ((t >> 3) & 3);
  const int srcslot = (l & 3) ^ ((l >> 3) & 3);
  const int frag_off = (l & 15) * 32 + ((((l >> 4) ^ (l >> 1)) & 3) * 8);
  const float* xrow = x + (mBase + xrow_l) * 1024;

#define K1_STAGE_B(k0, p)                                                     \
  {                                                                           \
    _Pragma("unroll") for (int c = 0; c < 2; ++c) {                           \
      int ch = c * 4 + w;                                                     \
      int row = ch * 16 + (l >> 2);                                           \
      gld_lds16(Th + (long)row * 1024 + (k0) + srcslot * 8, &Dh[p][ch * 512]);\
      gld_lds16(Tl + (long)row * 1024 + (k0) + srcslot * 8, &Dl[p][ch * 512]);\
    }                                                                         \
  }

#define K1_COMPUTE(p)                                                         \
  {                                                                           \
    bf16x8 dh[4], dl[4], xh[2], xl[2];                                        \
    _Pragma("unroll") for (int m = 0; m < 4; ++m) {                           \
      dh[m] = *reinterpret_cast<const bf16x8*>(&Dh[p][(wr * 64 + m * 16) * 32 + frag_off]); \
      dl[m] = *reinterpret_cast<const bf16x8*>(&Dl[p][(wr * 64 + m * 16) * 32 + frag_off]); \
    }                                                                         \
    _Pragma("unroll") for (int n = 0; n < 2; ++n) {                           \
      xh[n] = *reinterpret_cast<const bf16x8*>(&Xh[p][(wc * 32 + n * 16) * 32 + frag_off]); \
      xl[n] = *reinterpret_cast<const bf16x8*>(&Xl[p][(wc * 32 + n * 16) * 32 + frag_off]); \
    }                                                                         \
    _Pragma("unroll") for (int m = 0; m < 4; ++m)                             \
        _Pragma("unroll") for (int n = 0; n < 2; ++n) {                       \
      acc[m][n] = __builtin_amdgcn_mfma_f32_16x16x32_bf16(dh[m], xh[n], acc[m][n], 0, 0, 0); \
      acc[m][n] = __builtin_amdgcn_mfma_f32_16x16x32_bf16(dh[m], xl[n], acc[m][n], 0, 0, 0); \
      acc[m][n] = __builtin_amdgcn_mfma_f32_16x16x32_bf16(dl[m], xh[n], acc[m][n], 0, 0, 0); \
    }                                                                         \
  }

  {
    float4 p0 = *reinterpret_cast<const float4*>(&xrow[kslot * 8]);
    float4 p1 = *reinterpret_cast<const float4*>(&xrow[kslot * 8 + 4]);
    K1_STAGE_B(0, 0);
    split8_store(p0, p1, &Xh[0][xrow_l * 32 + xsl * 8], &Xl[0][xrow_l * 32 + xsl * 8]);
  }

  for (int k0 = 0; k0 < 1024; k0 += 64) {
    __syncthreads();
    float4 na0 = *reinterpret_cast<const float4*>(&xrow[k0 + 32 + kslot * 8]);
    float4 na1 = *reinterpret_cast<const float4*>(&xrow[k0 + 32 + kslot * 8 + 4]);
    K1_STAGE_B(k0 + 32, 1);
    K1_COMPUTE(0);
    split8_store(na0, na1, &Xh[1][xrow_l * 32 + xsl * 8], &Xl[1][xrow_l * 32 + xsl * 8]);
    __syncthreads();
    if (k0 + 64 < 1024) {
      float4 nb0 = *reinterpret_cast<const float4*>(&xrow[k0 + 64 + kslot * 8]);
      float4 nb1 = *reinterpret_cast<const float4*>(&xrow[k0 + 64 + kslot * 8 + 4]);
      K1_STAGE_B(k0 + 64, 0);
      K1_COMPUTE(1);
      split8_store(nb0, nb1, &Xh[0][xrow_l * 32 + xsl * 8], &Xl[0][xrow_l * 32 + xsl * 8]);
    } else {
      K1_COMPUTE(1);
    }
  }

#pragma unroll
  for (int m = 0; m < 4; ++m)
#pragma unroll
    for (int n = 0; n < 2; ++n) {
      int d0 = wr * 64 + m * 16 + (l >> 4) * 4;
      long xr = mBase + wc * 32 + n * 16 + (l & 15);
      *reinterpret_cast<float4*>(&qk[xr * 128 + d0]) =
          make_float4(acc[m][n][0], acc[m][n][1], acc[m][n][2], acc[m][n][3]);
    }
#undef K1_STAGE_B
#undef K1_COMPUTE
}

// -------- K2a: st[b,j,i] = exp(sigmoid(q_i . k_j)), split-bf16 MFMA -----------
// Single-stage: full K=64 staged once (LDS 64 KB), one barrier, 96 MFMA.
__global__ __launch_bounds__(256) void k2a_mfma(const float* __restrict__ qk,
                                                unsigned short* __restrict__ st) {
  __shared__ unsigned short Ah[128 * 64];
  __shared__ unsigned short Al[128 * 64];
  __shared__ unsigned short Bh[128 * 64];
  __shared__ unsigned short Bl[128 * 64];
  const int t = threadIdx.x;
  const int l = t & 63;
  const int w = t >> 6;
  const int wr = w >> 1, wc = w & 1;

  const int cpx = gridDim.x >> 3;
  const int orig = blockIdx.x;
  const int lw = (orig & 7) * cpx + (orig >> 3);
  const int b = lw >> 4;
  const int tile = lw & 15;
  const int iBase = (tile >> 2) * 128;
  const int jBase = (tile & 3) * 128;
  const float* qb = qk + (long)b * 512 * 128;

  // stage: thread (r = t>>1, khalf = t&1) stages 32 k of row r for A and B
  {
    const int r = t >> 1;
    const int kh = t & 1;
    const float* qa = &qb[(long)(iBase + r) * 128 + kh * 32];
    const float* kb = &qb[(long)(jBase + r) * 128 + 64 + kh * 32];
#pragma unroll
    for (int c = 0; c < 4; ++c) {
      int s = (kh * 4 + c) ^ (r & 7);
      float4 a0 = *reinterpret_cast<const float4*>(&qa[c * 8]);
      float4 a1 = *reinterpret_cast<const float4*>(&qa[c * 8 + 4]);
      split8_store(a0, a1, &Ah[r * 64 + s * 8], &Al[r * 64 + s * 8]);
      float4 b0 = *reinterpret_cast<const float4*>(&kb[c * 8]);
      float4 b1 = *reinterpret_cast<const float4*>(&kb[c * 8 + 4]);
      split8_store(b0, b1, &Bh[r * 64 + s * 8], &Bl[r * 64 + s * 8]);
    }
  }
  __syncthreads();

  f32x4 acc[4][4];
#pragma unroll
  for (int m = 0; m < 4; ++m)
#pragma unroll
    for (int n = 0; n < 4; ++n) acc[m][n] = (f32x4){0.f, 0.f, 0.f, 0.f};

#pragma unroll
  for (int ks = 0; ks < 2; ++ks) {
    bf16x8 ah[4], al4[4], bh[4], bl4[4];
#pragma unroll
    for (int m = 0; m < 4; ++m) {
      int row = wr * 64 + m * 16 + (l & 15);
      int off = row * 64 + ((ks * 4 + (l >> 4)) ^ (row & 7)) * 8;
      ah[m] = *reinterpret_cast<const bf16x8*>(&Ah[off]);
      al4[m] = *reinterpret_cast<const bf16x8*>(&Al[off]);
    }
#pragma unroll
    for (int n = 0; n < 4; ++n) {
      int row = wc * 64 + n * 16 + (l & 15);
      int off = row * 64 + ((ks * 4 + (l >> 4)) ^ (row & 7)) * 8;
      bh[n] = *reinterpret_cast<const bf16x8*>(&Bh[off]);
      bl4[n] = *reinterpret_cast<const bf16x8*>(&Bl[off]);
    }
#pragma unroll
    for (int m = 0; m < 4; ++m)
#pragma unroll
      for (int n = 0; n < 4; ++n) {
        acc[m][n] = __builtin_amdgcn_mfma_f32_16x16x32_bf16(ah[m], bh[n], acc[m][n], 0, 0, 0);
        acc[m][n] = __builtin_amdgcn_mfma_f32_16x16x32_bf16(ah[m], bl4[n], acc[m][n], 0, 0, 0);
        acc[m][n] = __builtin_amdgcn_mfma_f32_16x16x32_bf16(al4[m], bh[n], acc[m][n], 0, 0, 0);
      }
  }

  unsigned short* sb = st + (long)b * 512 * 512;
#pragma unroll
  for (int m = 0; m < 4; ++m)
#pragma unroll
    for (int n = 0; n < 4; ++n) {
      int i0 = iBase + wr * 64 + m * 16 + (l >> 4) * 4;
      int j = jBase + wc * 64 + n * 16 + (l & 15);
      unsigned short p[4];
#pragma unroll
      for (int reg = 0; reg < 4; ++reg) {
        float sg = 1.0f / (1.0f + __expf(-acc[m][n][reg]));
        p[reg] = f2bf(__expf(sg));
      }
      *reinterpret_cast<uint2*>(&sb[(long)j * 512 + i0]) = *reinterpret_cast<uint2*>(p);
    }
}

// -------- K2b: per-row (j) sums of st -> rsum = 1/sum, attbias = (st.bias)/sum ----
__global__ __launch_bounds__(256) void k2b_rsum(const unsigned short* __restrict__ st,
                                                const float* __restrict__ bias,
                                                float* __restrict__ rsum,
                                                float* __restrict__ attbias) {
  int jg = blockIdx.x * 4 + (threadIdx.x >> 6);
  int l = threadIdx.x & 63;
  const unsigned short* row = st + (long)jg * 512 + l * 8;
  ushort4 u0 = *reinterpret_cast<const ushort4*>(row);
  ushort4 u1 = *reinterpret_cast<const ushort4*>(row + 4);
  float4 b0 = *reinterpret_cast<const float4*>(&bias[l * 8]);
  float4 b1 = *reinterpret_cast<const float4*>(&bias[l * 8 + 4]);
  float f0 = bf2f(u0.x), f1 = bf2f(u0.y), f2 = bf2f(u0.z), f3 = bf2f(u0.w);
  float f4 = bf2f(u1.x), f5 = bf2f(u1.y), f6 = bf2f(u1.z), f7 = bf2f(u1.w);
  float sum = (f0 + f1) + (f2 + f3) + ((f4 + f5) + (f6 + f7));
  float sumb = f0 * b0.x + f1 * b0.y + f2 * b0.z + f3 * b0.w +
               f4 * b1.x + f5 * b1.y + f6 * b1.z + f7 * b1.w;
#pragma unroll
  for (int off = 32; off > 0; off >>= 1) {
    sum += __shfl_down(sum, off);
    sumb += __shfl_down(sumb, off);
  }
  if (l == 0) {
    float r = 1.0f / sum;
    rsum[jg] = r;
    attbias[jg] = sumb * r;
  }
}

// -------- transpose + fp32->bf16 convert: out[c][r] = bf16(in[r][c]) --------
__global__ __launch_bounds__(256) void transpose_conv(const float* __restrict__ in,
                                                      unsigned short* __restrict__ out,
                                                      int inRows, int inCols,
                                                      long inBatch, long outBatch) {
  __shared__ unsigned short lt[64][65];
  int b = blockIdx.z;
  int r0 = blockIdx.y * 64;
  int c0 = blockIdx.x * 64;
  const float* I = in + (long)b * inBatch;
  unsigned short* O = out + (long)b * outBatch;
  int t = threadIdx.x;
  int cl = (t & 15) * 4;
  int rl = t >> 4;
#pragma unroll
  for (int rr = 0; rr < 4; ++rr) {
    int r = rl + rr * 16;
    float4 v = *reinterpret_cast<const float4*>(&I[(long)(r0 + r) * inCols + c0 + cl]);
    lt[cl + 0][r] = f2bf(v.x);
    lt[cl + 1][r] = f2bf(v.y);
    lt[cl + 2][r] = f2bf(v.z);
    lt[cl + 3][r] = f2bf(v.w);
  }
  __syncthreads();
#pragma unroll
  for (int rr = 0; rr < 4; ++rr) {
    int c = rl + rr * 16;
    unsigned short v[4] = {lt[c][cl], lt[c][cl + 1], lt[c][cl + 2], lt[c][cl + 3]};
    *reinterpret_cast<uint2*>(&O[(long)(c0 + c) * inRows + r0 + cl]) =
        *reinterpret_cast<uint2*>(&v[0]);
  }
}

// ======== 256x256-tile bf16 MFMA GEMM, BK=64, 512 thr / 8 waves (2M x 4N) ========
// T4 counted-vmcnt pipeline: raw s_barrier (no drain), prefetch stays in flight.
// Per K-tile: compute(p) | barrier | stage(kt+2 -> p) | vmcnt(8) | barrier.
// vmcnt(8) is correct by construction: the stage's 8 loads are always the newest 8
// and the loop body issues no other vmem ops.
// MODE 0 (K3): A=vwT[c][i], B=st[b][j][i];  weff[b,j,c] = rsum[j] * D  (bf16)
// MODE 1 (K4): A=xbT[b][n][c], B=weff[b][j][c]; out[b,j,n] = D + attbias[j] (f32)
template <int MODE>
__global__ __launch_bounds__(512) void mfma_nt256(const unsigned short* __restrict__ Abase,
                                                  const unsigned short* __restrict__ Bbase,
                                                  const float* __restrict__ rowscale,
                                                  unsigned short* __restrict__ Wout,
                                                  float* __restrict__ Fout) {
  __shared__ unsigned short As[2][256 * 64];
  __shared__ unsigned short Bs[2][256 * 64];
  const int t = threadIdx.x;
  const int l = t & 63;
  const int w = t >> 6;          // 0..7
  const int wr = w >> 2;         // 0..1  (M: 2 x 128)
  const int wc = w & 3;          // 0..3  (N: 4 x 64)

  // XCD-chunked bijective swizzle; logical order: b-major, tiles inner
  const int cpx = gridDim.x >> 3;
  const int orig = blockIdx.x;
  const int lw = (orig & 7) * cpx + (orig >> 3);
  const int TPB_SH = (MODE == 0) ? 2 : 3;
  const int b = lw >> TPB_SH;
  const int tile = lw & ((1 << TPB_SH) - 1);
  const int mBase = (tile >> 1) * 256;
  const int nBase = (tile & 1) * 256;

  const unsigned short* Ag = Abase + ((MODE == 0) ? 0L : (long)b * (1024 * 512)) + (long)mBase * 512;
  const unsigned short* Bg = Bbase + (long)b * (512 * 512) + (long)nBase * 512;

  f32x4 acc[8][4];
#pragma unroll
  for (int m = 0; m < 8; ++m)
#pragma unroll
    for (int n = 0; n < 4; ++n) acc[m][n] = (f32x4){0.f, 0.f, 0.f, 0.f};

  const int srcslot = (l & 7) ^ (l >> 3);

#define NT_STAGE(kt, p)                                                        \
  {                                                                            \
    _Pragma("unroll") for (int pr = 0; pr < 4; ++pr) {                         \
      int rr = pr * 64 + w * 8 + (l >> 3);                                     \
      gld_lds16(Ag + (long)rr * 512 + (kt) * 64 + srcslot * 8,                 \
                &As[p][(pr * 64 + w * 8) * 64]);                               \
      gld_lds16(Bg + (long)rr * 512 + (kt) * 64 + srcslot * 8,                 \
                &Bs[p][(pr * 64 + w * 8) * 64]);                               \
    }                                                                          \
  }

#define NT_COMPUTE(p)                                                          \
  {                                                                            \
    _Pragma("unroll") for (int kk = 0; kk < 2; ++kk) {                         \
      const int so = ((kk * 4 + (l >> 4)) ^ (l & 7)) * 8;                      \
      bf16x8 af[8], bfr[4];                                                    \
      _Pragma("unroll") for (int m = 0; m < 8; ++m)                            \
        af[m] = *reinterpret_cast<const bf16x8*>(                              \
            &As[p][(wr * 128 + m * 16 + (l & 15)) * 64 + so]);                 \
      _Pragma("unroll") for (int n = 0; n < 4; ++n)                            \
        bfr[n] = *reinterpret_cast<const bf16x8*>(                             \
            &Bs[p][(wc * 64 + n * 16 + (l & 15)) * 64 + so]);                  \
      _Pragma("unroll") for (int m = 0; m < 8; ++m)                            \
        _Pragma("unroll") for (int n = 0; n < 4; ++n)                          \
          acc[m][n] = __builtin_amdgcn_mfma_f32_16x16x32_bf16(af[m], bfr[n],   \
                                                              acc[m][n], 0, 0, 0); \
    }                                                                          \
  }

  // prologue: tiles 0 and 1 in flight; wait tile 0 (8 newest = tile 1 stay in flight)
  NT_STAGE(0, 0);
  NT_STAGE(1, 1);
  VMW(8);
  NTBAR();

  for (int kt = 0; kt < 8; ++kt) {
    const int p = kt & 1;
    __builtin_amdgcn_s_setprio(1);
    NT_COMPUTE(p);
    __builtin_amdgcn_s_setprio(0);
    NTBAR();                    // all waves done reading buf p (no counter drain)
    if (kt < 6) {
      NT_STAGE(kt + 2, p);      // refill freed buffer
      VMW(8);                   // tile kt+1 landed (only kt+2's 8 outstanding)
    } else {
      VMW(0);                   // tail drain
    }
    NTBAR();                    // buf p^1 ready for next iteration
  }
#undef NT_STAGE
#undef NT_COMPUTE

  if (MODE == 0) {
    unsigned short* W = Wout + (long)b * (512 * 512);
#pragma unroll
    for (int n = 0; n < 4; ++n) {
      int j = nBase + wc * 64 + n * 16 + (l & 15);
      float rs = rowscale[b * 512 + j];
#pragma unroll
      for (int m = 0; m < 8; ++m) {
        int c0 = mBase + wr * 128 + m * 16 + (l >> 4) * 4;
        unsigned short p[4];
#pragma unroll
        for (int reg = 0; reg < 4; ++reg) p[reg] = f2bf(acc[m][n][reg] * rs);
        *reinterpret_cast<uint2*>(&W[(long)j * 512 + c0]) = *reinterpret_cast<uint2*>(p);
      }
    }
  } else {
    float* O = Fout + (long)b * (512 * 1024);
#pragma unroll
    for (int n = 0; n < 4; ++n) {
      int j = nBase + wc * 64 + n * 16 + (l & 15);
      float ab = rowscale[b * 512 + j];
#pragma unroll
      for (int m = 0; m < 8; ++m) {
        int n0 = mBase + wr * 128 + m * 16 + (l >> 4) * 4;
        *reinterpret_cast<float4*>(&O[(long)j * 1024 + n0]) =
            make_float4(acc[m][n][0] + ab, acc[m][n][1] + ab,
                        acc[m][n][2] + ab, acc[m][n][3] + ab);
      }
    }
  }
}

extern "C" void kernel_launch(void* const* d_in, const int* in_sizes, int n_in,
                              void* d_out, int out_size, void* d_ws, size_t ws_size,
                              hipStream_t stream) {
  const float* x  = (const float*)d_in[0];
  const float* Qm = (const float*)d_in[1];
  const float* Km = (const float*)d_in[2];
  const float* vw = (const float*)d_in[3];
  const float* vb = (const float*)d_in[4];
  float* out = (float*)d_out;

  float* ws = (float*)d_ws;
  float* qk = ws;                                                     // 4,194,304 f
  unsigned short* st   = (unsigned short*)(ws + 4194304);             // spans 8,388,608 f
  unsigned short* weff = (unsigned short*)(ws + 4194304 + 8388608);   // spans 8,388,608 f
  unsigned short* xbT  = (unsigned short*)(ws + 4194304 + 16777216);  // spans 16,777,216 f
  unsigned short* vwT  = (unsigned short*)(ws + 4194304 + 33554432);  // spans 131,072 f
  unsigned short* qkTh = (unsigned short*)(ws + 4194304 + 33554432 + 131072);  // 65,536 f
  unsigned short* qkTl = qkTh + 131072;                               // 65,536 f
  float* rsum    = ws + 4194304 + 33554432 + 131072 + 131072;         // 32,768 f
  float* attbias = rsum + 32768;                                      // 32,768 f

  // T1: xbT[b][n][c] = bf16(x[b][c][n])
  transpose_conv<<<dim3(16, 8, 64), 256, 0, stream>>>(x, xbT, 512, 1024, 524288L, 524288L);
  // T2: vwT[c][i] = bf16(vw[i][c])
  transpose_conv<<<dim3(8, 8, 1), 256, 0, stream>>>(vw, vwT, 512, 512, 0L, 0L);
  // T3: split-transposed [Qm|Km] -> qkTh/qkTl [128][1024]
  qkm_split<<<dim3(16, 2), 256, 0, stream>>>(Qm, Km, qkTh, qkTl);
  // K1: qk = x @ [Qm|Km], split-bf16 MFMA (dbuf pipeline)
  k1_mfma<<<512, 256, 0, stream>>>(x, qkTh, qkTl, qk);
  // K2a: st[b,j,i] = exp(sigmoid(q_i . k_j)), split-bf16 MFMA (single-stage)
  k2a_mfma<<<1024, 256, 0, stream>>>(qk, st);
  // K2b: rsum, attbias
  k2b_rsum<<<8192, 256, 0, stream>>>(st, vb, rsum, attbias);
  // K3: weff = diag(rsum) . st . Vw   (A=vwT, B=st), 4 tiles/b
  mfma_nt256<0><<<256, 512, 0, stream>>>(vwT, st, rsum, weff, nullptr);
  // K4: out = weff . xf + attbias     (A=xbT, B=weff), 8 tiles/b
  mfma_nt256<1><<<512, 512, 0, stream>>>(xbT, weff, attbias, nullptr, out);
}

// Round 8
// 212.734 us; speedup vs baseline: 1.1142x; 1.0410x over previous
//
#include <hip/hip_runtime.h>

#define BK 32

typedef __attribute__((ext_vector_type(8))) short bf16x8;
typedef __attribute__((ext_vector_type(4))) float f32x4;

__device__ __forceinline__ unsigned short f2bf(float f) {
  unsigned u = __builtin_bit_cast(unsigned, f);
  unsigned r = (u + 0x7FFFu + ((u >> 16) & 1u)) >> 16;
  return (unsigned short)r;
}
__device__ __forceinline__ float bf2f(unsigned short h) {
  return __builtin_bit_cast(float, (unsigned)h << 16);
}
__device__ __forceinline__ unsigned pack2(unsigned short a, unsigned short b) {
  return (unsigned)a | ((unsigned)b << 16);
}

__device__ __forceinline__ void gld_lds16(const void* g, void* l) {
  __builtin_amdgcn_global_load_lds(
      (const __attribute__((address_space(1))) unsigned int*)g,
      (__attribute__((address_space(3))) unsigned int*)l, 16, 0, 0);
}

#define SCHED0() __builtin_amdgcn_sched_barrier(0)
#define NTBAR() do { SCHED0(); __builtin_amdgcn_s_barrier(); SCHED0(); } while (0)
#define VMW(N) do { asm volatile("s_waitcnt vmcnt(" #N ")" ::: "memory"); SCHED0(); } while (0)
#define LGKM0() do { asm volatile("s_waitcnt lgkmcnt(0)" ::: "memory"); SCHED0(); } while (0)
#define MFMA16(a, b, c) __builtin_amdgcn_mfma_f32_16x16x32_bf16(a, b, c, 0, 0, 0)

// split 8 fp32 -> hi/lo bf16, store as uint4 pair (ds_write_b128)
__device__ __forceinline__ void split8_store(float4 v0, float4 v1,
                                             unsigned short* Hdst,
                                             unsigned short* Ldst) {
  float f[8] = {v0.x, v0.y, v0.z, v0.w, v1.x, v1.y, v1.z, v1.w};
  unsigned short hh[8], ll[8];
#pragma unroll
  for (int i = 0; i < 8; ++i) {
    hh[i] = f2bf(f[i]);
    ll[i] = f2bf(f[i] - bf2f(hh[i]));
  }
  *reinterpret_cast<uint4*>(Hdst) = make_uint4(pack2(hh[0], hh[1]), pack2(hh[2], hh[3]),
                                               pack2(hh[4], hh[5]), pack2(hh[6], hh[7]));
  *reinterpret_cast<uint4*>(Ldst) = make_uint4(pack2(ll[0], ll[1]), pack2(ll[2], ll[3]),
                                               pack2(ll[4], ll[5]), pack2(ll[6], ll[7]));
}

// -------- QB prep: Th/Tl[d][k] = split-bf16 of [Qm | Km] column d --------
__global__ __launch_bounds__(256) void qkm_split(const float* __restrict__ Qm,
                                                 const float* __restrict__ Km,
                                                 unsigned short* __restrict__ Th,
                                                 unsigned short* __restrict__ Tl) {
  __shared__ float lt[64][65];
  int k0 = blockIdx.x * 64;
  int half = blockIdx.y;
  const float* M = half ? Km : Qm;
  int t = threadIdx.x;
  int cl = (t & 15) * 4;
  int rl = t >> 4;
#pragma unroll
  for (int rr = 0; rr < 4; ++rr) {
    int r = rl + rr * 16;
    float4 v = *reinterpret_cast<const float4*>(&M[(long)(k0 + r) * 64 + cl]);
    lt[cl + 0][r] = v.x;
    lt[cl + 1][r] = v.y;
    lt[cl + 2][r] = v.z;
    lt[cl + 3][r] = v.w;
  }
  __syncthreads();
#pragma unroll
  for (int rr = 0; rr < 4; ++rr) {
    int c = rl + rr * 16;
    unsigned short h[4], lo[4];
#pragma unroll
    for (int i = 0; i < 4; ++i) {
      float f = lt[c][cl + i];
      h[i] = f2bf(f);
      lo[i] = f2bf(f - bf2f(h[i]));
    }
    *reinterpret_cast<uint2*>(&Th[(long)(half * 64 + c) * 1024 + k0 + cl]) =
        make_uint2(pack2(h[0], h[1]), pack2(h[2], h[3]));
    *reinterpret_cast<uint2*>(&Tl[(long)(half * 64 + c) * 1024 + k0 + cl]) =
        make_uint2(pack2(lo[0], lo[1]), pack2(lo[2], lo[3]));
  }
}

// -------- K1: qk[32768,128] = x @ [Qm|Km], split-bf16 MFMA, dbuf pipeline --------
__global__ __launch_bounds__(256) void k1_mfma(const float* __restrict__ x,
                                               const unsigned short* __restrict__ Th,
                                               const unsigned short* __restrict__ Tl,
                                               float* __restrict__ qk) {
  __shared__ unsigned short Dh[2][128 * 32];
  __shared__ unsigned short Dl[2][128 * 32];
  __shared__ unsigned short Xh[2][64 * 32];
  __shared__ unsigned short Xl[2][64 * 32];
  const int t = threadIdx.x;
  const int l = t & 63;
  const int w = t >> 6;
  const int wr = w >> 1, wc = w & 1;
  const long mBase = (long)blockIdx.x * 64;

  f32x4 acc[4][2];
#pragma unroll
  for (int m = 0; m < 4; ++m)
#pragma unroll
    for (int n = 0; n < 2; ++n) acc[m][n] = (f32x4){0.f, 0.f, 0.f, 0.f};

  const int xrow_l = t >> 2;
  const int kslot = t & 3;
  const int xsl = kslot ^ ((t >> 3) & 3);
  const int srcslot = (l & 3) ^ ((l >> 3) & 3);
  const int frag_off = (l & 15) * 32 + ((((l >> 4) ^ (l >> 1)) & 3) * 8);
  const float* xrow = x + (mBase + xrow_l) * 1024;

#define K1_STAGE_B(k0, p)                                                     \
  {                                                                           \
    _Pragma("unroll") for (int c = 0; c < 2; ++c) {                           \
      int ch = c * 4 + w;                                                     \
      int row = ch * 16 + (l >> 2);                                           \
      gld_lds16(Th + (long)row * 1024 + (k0) + srcslot * 8, &Dh[p][ch * 512]);\
      gld_lds16(Tl + (long)row * 1024 + (k0) + srcslot * 8, &Dl[p][ch * 512]);\
    }                                                                         \
  }

#define K1_COMPUTE(p)                                                         \
  {                                                                           \
    bf16x8 dh[4], dl[4], xh[2], xl[2];                                        \
    _Pragma("unroll") for (int m = 0; m < 4; ++m) {                           \
      dh[m] = *reinterpret_cast<const bf16x8*>(&Dh[p][(wr * 64 + m * 16) * 32 + frag_off]); \
      dl[m] = *reinterpret_cast<const bf16x8*>(&Dl[p][(wr * 64 + m * 16) * 32 + frag_off]); \
    }                                                                         \
    _Pragma("unroll") for (int n = 0; n < 2; ++n) {                           \
      xh[n] = *reinterpret_cast<const bf16x8*>(&Xh[p][(wc * 32 + n * 16) * 32 + frag_off]); \
      xl[n] = *reinterpret_cast<const bf16x8*>(&Xl[p][(wc * 32 + n * 16) * 32 + frag_off]); \
    }                                                                         \
    _Pragma("unroll") for (int m = 0; m < 4; ++m)                             \
        _Pragma("unroll") for (int n = 0; n < 2; ++n) {                       \
      acc[m][n] = MFMA16(dh[m], xh[n], acc[m][n]);                            \
      acc[m][n] = MFMA16(dh[m], xl[n], acc[m][n]);                            \
      acc[m][n] = MFMA16(dl[m], xh[n], acc[m][n]);                            \
    }                                                                         \
  }

  {
    float4 p0 = *reinterpret_cast<const float4*>(&xrow[kslot * 8]);
    float4 p1 = *reinterpret_cast<const float4*>(&xrow[kslot * 8 + 4]);
    K1_STAGE_B(0, 0);
    split8_store(p0, p1, &Xh[0][xrow_l * 32 + xsl * 8], &Xl[0][xrow_l * 32 + xsl * 8]);
  }

  for (int k0 = 0; k0 < 1024; k0 += 64) {
    __syncthreads();
    float4 na0 = *reinterpret_cast<const float4*>(&xrow[k0 + 32 + kslot * 8]);
    float4 na1 = *reinterpret_cast<const float4*>(&xrow[k0 + 32 + kslot * 8 + 4]);
    K1_STAGE_B(k0 + 32, 1);
    K1_COMPUTE(0);
    split8_store(na0, na1, &Xh[1][xrow_l * 32 + xsl * 8], &Xl[1][xrow_l * 32 + xsl * 8]);
    __syncthreads();
    if (k0 + 64 < 1024) {
      float4 nb0 = *reinterpret_cast<const float4*>(&xrow[k0 + 64 + kslot * 8]);
      float4 nb1 = *reinterpret_cast<const float4*>(&xrow[k0 + 64 + kslot * 8 + 4]);
      K1_STAGE_B(k0 + 64, 0);
      K1_COMPUTE(1);
      split8_store(nb0, nb1, &Xh[0][xrow_l * 32 + xsl * 8], &Xl[0][xrow_l * 32 + xsl * 8]);
    } else {
      K1_COMPUTE(1);
    }
  }

#pragma unroll
  for (int m = 0; m < 4; ++m)
#pragma unroll
    for (int n = 0; n < 2; ++n) {
      int d0 = wr * 64 + m * 16 + (l >> 4) * 4;
      long xr = mBase + wc * 32 + n * 16 + (l & 15);
      *reinterpret_cast<float4*>(&qk[xr * 128 + d0]) =
          make_float4(acc[m][n][0], acc[m][n][1], acc[m][n][2], acc[m][n][3]);
    }
#undef K1_STAGE_B
#undef K1_COMPUTE
}

// -------- K2a: st[b,j,i] = exp(sigmoid(q_i . k_j)), split-bf16 MFMA -----------
__global__ __launch_bounds__(256) void k2a_mfma(const float* __restrict__ qk,
                                                unsigned short* __restrict__ st) {
  __shared__ unsigned short Ah[128 * 64];
  __shared__ unsigned short Al[128 * 64];
  __shared__ unsigned short Bh[128 * 64];
  __shared__ unsigned short Bl[128 * 64];
  const int t = threadIdx.x;
  const int l = t & 63;
  const int w = t >> 6;
  const int wr = w >> 1, wc = w & 1;

  const int cpx = gridDim.x >> 3;
  const int orig = blockIdx.x;
  const int lw = (orig & 7) * cpx + (orig >> 3);
  const int b = lw >> 4;
  const int tile = lw & 15;
  const int iBase = (tile >> 2) * 128;
  const int jBase = (tile & 3) * 128;
  const float* qb = qk + (long)b * 512 * 128;

  {
    const int r = t >> 1;
    const int kh = t & 1;
    const float* qa = &qb[(long)(iBase + r) * 128 + kh * 32];
    const float* kb = &qb[(long)(jBase + r) * 128 + 64 + kh * 32];
#pragma unroll
    for (int c = 0; c < 4; ++c) {
      int s = (kh * 4 + c) ^ (r & 7);
      float4 a0 = *reinterpret_cast<const float4*>(&qa[c * 8]);
      float4 a1 = *reinterpret_cast<const float4*>(&qa[c * 8 + 4]);
      split8_store(a0, a1, &Ah[r * 64 + s * 8], &Al[r * 64 + s * 8]);
      float4 b0 = *reinterpret_cast<const float4*>(&kb[c * 8]);
      float4 b1 = *reinterpret_cast<const float4*>(&kb[c * 8 + 4]);
      split8_store(b0, b1, &Bh[r * 64 + s * 8], &Bl[r * 64 + s * 8]);
    }
  }
  __syncthreads();

  f32x4 acc[4][4];
#pragma unroll
  for (int m = 0; m < 4; ++m)
#pragma unroll
    for (int n = 0; n < 4; ++n) acc[m][n] = (f32x4){0.f, 0.f, 0.f, 0.f};

#pragma unroll
  for (int ks = 0; ks < 2; ++ks) {
    bf16x8 ah[4], al4[4], bh[4], bl4[4];
#pragma unroll
    for (int m = 0; m < 4; ++m) {
      int row = wr * 64 + m * 16 + (l & 15);
      int off = row * 64 + ((ks * 4 + (l >> 4)) ^ (row & 7)) * 8;
      ah[m] = *reinterpret_cast<const bf16x8*>(&Ah[off]);
      al4[m] = *reinterpret_cast<const bf16x8*>(&Al[off]);
    }
#pragma unroll
    for (int n = 0; n < 4; ++n) {
      int row = wc * 64 + n * 16 + (l & 15);
      int off = row * 64 + ((ks * 4 + (l >> 4)) ^ (row & 7)) * 8;
      bh[n] = *reinterpret_cast<const bf16x8*>(&Bh[off]);
      bl4[n] = *reinterpret_cast<const bf16x8*>(&Bl[off]);
    }
#pragma unroll
    for (int m = 0; m < 4; ++m)
#pragma unroll
      for (int n = 0; n < 4; ++n) {
        acc[m][n] = MFMA16(ah[m], bh[n], acc[m][n]);
        acc[m][n] = MFMA16(ah[m], bl4[n], acc[m][n]);
        acc[m][n] = MFMA16(al4[m], bh[n], acc[m][n]);
      }
  }

  unsigned short* sb = st + (long)b * 512 * 512;
#pragma unroll
  for (int m = 0; m < 4; ++m)
#pragma unroll
    for (int n = 0; n < 4; ++n) {
      int i0 = iBase + wr * 64 + m * 16 + (l >> 4) * 4;
      int j = jBase + wc * 64 + n * 16 + (l & 15);
      unsigned short p[4];
#pragma unroll
      for (int reg = 0; reg < 4; ++reg) {
        float sg = 1.0f / (1.0f + __expf(-acc[m][n][reg]));
        p[reg] = f2bf(__expf(sg));
      }
      *reinterpret_cast<uint2*>(&sb[(long)j * 512 + i0]) = *reinterpret_cast<uint2*>(p);
    }
}

// -------- K2b: per-row (j) sums of st -> rsum = 1/sum, attbias = (st.bias)/sum ----
__global__ __launch_bounds__(256) void k2b_rsum(const unsigned short* __restrict__ st,
                                                const float* __restrict__ bias,
                                                float* __restrict__ rsum,
                                                float* __restrict__ attbias) {
  int jg = blockIdx.x * 4 + (threadIdx.x >> 6);
  int l = threadIdx.x & 63;
  const unsigned short* row = st + (long)jg * 512 + l * 8;
  ushort4 u0 = *reinterpret_cast<const ushort4*>(row);
  ushort4 u1 = *reinterpret_cast<const ushort4*>(row + 4);
  float4 b0 = *reinterpret_cast<const float4*>(&bias[l * 8]);
  float4 b1 = *reinterpret_cast<const float4*>(&bias[l * 8 + 4]);
  float f0 = bf2f(u0.x), f1 = bf2f(u0.y), f2 = bf2f(u0.z), f3 = bf2f(u0.w);
  float f4 = bf2f(u1.x), f5 = bf2f(u1.y), f6 = bf2f(u1.z), f7 = bf2f(u1.w);
  float sum = (f0 + f1) + (f2 + f3) + ((f4 + f5) + (f6 + f7));
  float sumb = f0 * b0.x + f1 * b0.y + f2 * b0.z + f3 * b0.w +
               f4 * b1.x + f5 * b1.y + f6 * b1.z + f7 * b1.w;
#pragma unroll
  for (int off = 32; off > 0; off >>= 1) {
    sum += __shfl_down(sum, off);
    sumb += __shfl_down(sumb, off);
  }
  if (l == 0) {
    float r = 1.0f / sum;
    rsum[jg] = r;
    attbias[jg] = sumb * r;
  }
}

// -------- transpose + fp32->bf16 convert: out[c][r] = bf16(in[r][c]) --------
__global__ __launch_bounds__(256) void transpose_conv(const float* __restrict__ in,
                                                      unsigned short* __restrict__ out,
                                                      int inRows, int inCols,
                                                      long inBatch, long outBatch) {
  __shared__ unsigned short lt[64][65];
  int b = blockIdx.z;
  int r0 = blockIdx.y * 64;
  int c0 = blockIdx.x * 64;
  const float* I = in + (long)b * inBatch;
  unsigned short* O = out + (long)b * outBatch;
  int t = threadIdx.x;
  int cl = (t & 15) * 4;
  int rl = t >> 4;
#pragma unroll
  for (int rr = 0; rr < 4; ++rr) {
    int r = rl + rr * 16;
    float4 v = *reinterpret_cast<const float4*>(&I[(long)(r0 + r) * inCols + c0 + cl]);
    lt[cl + 0][r] = f2bf(v.x);
    lt[cl + 1][r] = f2bf(v.y);
    lt[cl + 2][r] = f2bf(v.z);
    lt[cl + 3][r] = f2bf(v.w);
  }
  __syncthreads();
#pragma unroll
  for (int rr = 0; rr < 4; ++rr) {
    int c = rl + rr * 16;
    unsigned short v[4] = {lt[c][cl], lt[c][cl + 1], lt[c][cl + 2], lt[c][cl + 3]};
    *reinterpret_cast<uint2*>(&O[(long)(c0 + c) * inRows + r0 + cl]) =
        *reinterpret_cast<uint2*>(&v[0]);
  }
}

// ======== 256x256 bf16 MFMA GEMM, BK=64, 8 waves, 8-PHASE schedule (m201) ========
// Iteration = 2 K-tiles (buf0, buf1), 8 phases. Phase q&3 computes m-quad {2q,2q+1}
// (16 MFMA), reads 4 A-frags (+8 B-frags in quad-0), prefetches one half-tile
// (2 gld_lds). Counted vmcnt: VMW(10)@ph1/ph5, VMW(8)@ph3/ph7 — never 0 in loop.
// Half-tile schedule (derived from consumption map; B free after quad0, Ha after
// quad1, Hb after quad3):
//   ph0: Hb->buf1(t1)  ph1: B0->buf0(t2)  ph2: B1->buf0(t2)  ph3: Ha->buf0(t2)
//   ph4: Hb->buf0(t2)  ph5: B0->buf1(t3)  ph6: B1->buf1(t3)  ph7: Ha->buf1(t3)
// Last iteration clamps t2/t3 to 7: dummy re-stages hit only already-consumed
// halves and keep the vmcnt counts uniform.
// MODE 0 (K3): A=vwT[c][i], B=st[b][j][i];  weff[b,j,c] = rsum[j] * D  (bf16)
// MODE 1 (K4): A=xbT[b][n][c], B=weff[b][j][c]; out[b,j,n] = D + attbias[j] (f32)
template <int MODE>
__global__ __launch_bounds__(512) void mfma_nt256(const unsigned short* __restrict__ Abase,
                                                  const unsigned short* __restrict__ Bbase,
                                                  const float* __restrict__ rowscale,
                                                  unsigned short* __restrict__ Wout,
                                                  float* __restrict__ Fout) {
  __shared__ unsigned short As[2][256 * 64];
  __shared__ unsigned short Bs[2][256 * 64];
  const int t = threadIdx.x;
  const int l = t & 63;
  const int w = t >> 6;          // 0..7
  const int wr = w >> 2;         // 0..1  (M: 2 x 128)
  const int wc = w & 3;          // 0..3  (N: 4 x 64)

  // XCD-chunked bijective swizzle; logical order: b-major, tiles inner
  const int cpx = gridDim.x >> 3;
  const int orig = blockIdx.x;
  const int lw = (orig & 7) * cpx + (orig >> 3);
  const int TPB_SH = (MODE == 0) ? 2 : 3;
  const int b = lw >> TPB_SH;
  const int tile = lw & ((1 << TPB_SH) - 1);
  const int mBase = (tile >> 1) * 256;
  const int nBase = (tile & 1) * 256;

  const unsigned short* Ag = Abase + ((MODE == 0) ? 0L : (long)b * (1024 * 512)) + (long)mBase * 512;
  const unsigned short* Bg = Bbase + (long)b * (512 * 512) + (long)nBase * 512;

  f32x4 acc[8][4];
#pragma unroll
  for (int m = 0; m < 8; ++m)
#pragma unroll
    for (int n = 0; n < 4; ++n) acc[m][n] = (f32x4){0.f, 0.f, 0.f, 0.f};

  const int srcslot = (l & 7) ^ (l >> 3);
  const int so0 = ((l >> 4) ^ (l & 7)) * 8;
  const int so1 = ((4 + (l >> 4)) ^ (l & 7)) * 8;

#define STG_A(p, tt, pr)                                                       \
  gld_lds16(Ag + (long)((pr) * 64 + w * 8 + (l >> 3)) * 512 + (tt) * 64 + srcslot * 8, \
            &As[p][((pr) * 64 + w * 8) * 64]);
#define STG_B(p, tt, pr)                                                       \
  gld_lds16(Bg + (long)((pr) * 64 + w * 8 + (l >> 3)) * 512 + (tt) * 64 + srcslot * 8, \
            &Bs[p][((pr) * 64 + w * 8) * 64]);

#define PHASE(p, q, STAGE_STMT, VMSTMT)                                        \
  {                                                                            \
    bf16x8 a00 = *reinterpret_cast<const bf16x8*>(                             \
        &As[p][(wr * 128 + (2 * (q)) * 16 + (l & 15)) * 64 + so0]);            \
    bf16x8 a01 = *reinterpret_cast<const bf16x8*>(                             \
        &As[p][(wr * 128 + (2 * (q)) * 16 + (l & 15)) * 64 + so1]);            \
    bf16x8 a10 = *reinterpret_cast<const bf16x8*>(                             \
        &As[p][(wr * 128 + (2 * (q) + 1) * 16 + (l & 15)) * 64 + so0]);        \
    bf16x8 a11 = *reinterpret_cast<const bf16x8*>(                             \
        &As[p][(wr * 128 + (2 * (q) + 1) * 16 + (l & 15)) * 64 + so1]);        \
    if ((q) == 0) {                                                            \
      _Pragma("unroll") for (int n = 0; n < 4; ++n) {                          \
        bfr0[n] = *reinterpret_cast<const bf16x8*>(                            \
            &Bs[p][(wc * 64 + n * 16 + (l & 15)) * 64 + so0]);                 \
        bfr1[n] = *reinterpret_cast<const bf16x8*>(                            \
            &Bs[p][(wc * 64 + n * 16 + (l & 15)) * 64 + so1]);                 \
      }                                                                        \
    }                                                                          \
    STAGE_STMT;                                                                \
    SCHED0();                                                                  \
    __builtin_amdgcn_s_barrier();                                              \
    LGKM0();                                                                   \
    __builtin_amdgcn_s_setprio(1);                                             \
    _Pragma("unroll") for (int n = 0; n < 4; ++n) {                            \
      acc[2 * (q)][n] = MFMA16(a00, bfr0[n], acc[2 * (q)][n]);                 \
      acc[2 * (q)][n] = MFMA16(a01, bfr1[n], acc[2 * (q)][n]);                 \
      acc[2 * (q) + 1][n] = MFMA16(a10, bfr0[n], acc[2 * (q) + 1][n]);         \
      acc[2 * (q) + 1][n] = MFMA16(a11, bfr1[n], acc[2 * (q) + 1][n]);         \
    }                                                                          \
    __builtin_amdgcn_s_setprio(0);                                             \
    VMSTMT;                                                                    \
    NTBAR();                                                                   \
  }

  bf16x8 bfr0[4], bfr1[4];

  // prologue: buf0 <- tile0 (8 loads), buf1 <- B0,B1,Ha of tile1 (6 loads)
  STG_A(0, 0, 0); STG_A(0, 0, 1); STG_A(0, 0, 2); STG_A(0, 0, 3);
  STG_B(0, 0, 0); STG_B(0, 0, 1); STG_B(0, 0, 2); STG_B(0, 0, 3);
  STG_B(1, 1, 0); STG_B(1, 1, 1); STG_B(1, 1, 2); STG_B(1, 1, 3);
  STG_A(1, 1, 0); STG_A(1, 1, 2);
  VMW(6);
  NTBAR();

  for (int it = 0; it < 4; ++it) {
    const int t1 = 2 * it + 1;
    const int t2 = (2 * it + 2 < 8) ? 2 * it + 2 : 7;
    const int t3 = (2 * it + 3 < 8) ? 2 * it + 3 : 7;
    PHASE(0, 0, { STG_A(1, t1, 1); STG_A(1, t1, 3); }, );
    PHASE(0, 1, { STG_B(0, t2, 0); STG_B(0, t2, 1); }, VMW(10));
    PHASE(0, 2, { STG_B(0, t2, 2); STG_B(0, t2, 3); }, );
    PHASE(0, 3, { STG_A(0, t2, 0); STG_A(0, t2, 2); }, VMW(8));
    PHASE(1, 0, { STG_A(0, t2, 1); STG_A(0, t2, 3); }, );
    PHASE(1, 1, { STG_B(1, t3, 0); STG_B(1, t3, 1); }, VMW(10));
    PHASE(1, 2, { STG_B(1, t3, 2); STG_B(1, t3, 3); }, );
    PHASE(1, 3, { STG_A(1, t3, 0); STG_A(1, t3, 2); }, VMW(8));
  }
#undef PHASE
#undef STG_A
#undef STG_B

  if (MODE == 0) {
    unsigned short* W = Wout + (long)b * (512 * 512);
#pragma unroll
    for (int n = 0; n < 4; ++n) {
      int j = nBase + wc * 64 + n * 16 + (l & 15);
      float rs = rowscale[b * 512 + j];
#pragma unroll
      for (int m = 0; m < 8; ++m) {
        int c0 = mBase + wr * 128 + m * 16 + (l >> 4) * 4;
        unsigned short p[4];
#pragma unroll
        for (int reg = 0; reg < 4; ++reg) p[reg] = f2bf(acc[m][n][reg] * rs);
        *reinterpret_cast<uint2*>(&W[(long)j * 512 + c0]) = *reinterpret_cast<uint2*>(p);
      }
    }
  } else {
    float* O = Fout + (long)b * (512 * 1024);
#pragma unroll
    for (int n = 0; n < 4; ++n) {
      int j = nBase + wc * 64 + n * 16 + (l & 15);
      float ab = rowscale[b * 512 + j];
#pragma unroll
      for (int m = 0; m < 8; ++m) {
        int n0 = mBase + wr * 128 + m * 16 + (l >> 4) * 4;
        *reinterpret_cast<float4*>(&O[(long)j * 1024 + n0]) =
            make_float4(acc[m][n][0] + ab, acc[m][n][1] + ab,
                        acc[m][n][2] + ab, acc[m][n][3] + ab);
      }
    }
  }
}

extern "C" void kernel_launch(void* const* d_in, const int* in_sizes, int n_in,
                              void* d_out, int out_size, void* d_ws, size_t ws_size,
                              hipStream_t stream) {
  const float* x  = (const float*)d_in[0];
  const float* Qm = (const float*)d_in[1];
  const float* Km = (const float*)d_in[2];
  const float* vw = (const float*)d_in[3];
  const float* vb = (const float*)d_in[4];
  float* out = (float*)d_out;

  float* ws = (float*)d_ws;
  float* qk = ws;                                                     // 4,194,304 f
  unsigned short* st   = (unsigned short*)(ws + 4194304);             // spans 8,388,608 f
  unsigned short* weff = (unsigned short*)(ws + 4194304 + 8388608);   // spans 8,388,608 f
  unsigned short* xbT  = (unsigned short*)(ws + 4194304 + 16777216);  // spans 16,777,216 f
  unsigned short* vwT  = (unsigned short*)(ws + 4194304 + 33554432);  // spans 131,072 f
  unsigned short* qkTh = (unsigned short*)(ws + 4194304 + 33554432 + 131072);  // 65,536 f
  unsigned short* qkTl = qkTh + 131072;                               // 65,536 f
  float* rsum    = ws + 4194304 + 33554432 + 131072 + 131072;         // 32,768 f
  float* attbias = rsum + 32768;                                      // 32,768 f

  // T1: xbT[b][n][c] = bf16(x[b][c][n])
  transpose_conv<<<dim3(16, 8, 64), 256, 0, stream>>>(x, xbT, 512, 1024, 524288L, 524288L);
  // T2: vwT[c][i] = bf16(vw[i][c])
  transpose_conv<<<dim3(8, 8, 1), 256, 0, stream>>>(vw, vwT, 512, 512, 0L, 0L);
  // T3: split-transposed [Qm|Km] -> qkTh/qkTl [128][1024]
  qkm_split<<<dim3(16, 2), 256, 0, stream>>>(Qm, Km, qkTh, qkTl);
  // K1: qk = x @ [Qm|Km], split-bf16 MFMA (dbuf pipeline)
  k1_mfma<<<512, 256, 0, stream>>>(x, qkTh, qkTl, qk);
  // K2a: st[b,j,i] = exp(sigmoid(q_i . k_j)), split-bf16 MFMA (single-stage)
  k2a_mfma<<<1024, 256, 0, stream>>>(qk, st);
  // K2b: rsum, attbias
  k2b_rsum<<<8192, 256, 0, stream>>>(st, vb, rsum, attbias);
  // K3: weff = diag(rsum) . st . Vw   (A=vwT, B=st), 4 tiles/b
  mfma_nt256<0><<<256, 512, 0, stream>>>(vwT, st, rsum, weff, nullptr);
  // K4: out = weff . xf + attbias     (A=xbT, B=weff), 8 tiles/b
  mfma_nt256<1><<<512, 512, 0, stream>>>(xbT, weff, attbias, nullptr, out);
}

// Round 9
// 204.796 us; speedup vs baseline: 1.1574x; 1.0388x over previous
//
#include <hip/hip_runtime.h>

#define BK 32

typedef __attribute__((ext_vector_type(8))) short bf16x8;
typedef __attribute__((ext_vector_type(4))) float f32x4;

__device__ __forceinline__ unsigned short f2bf(float f) {
  unsigned u = __builtin_bit_cast(unsigned, f);
  unsigned r = (u + 0x7FFFu + ((u >> 16) & 1u)) >> 16;
  return (unsigned short)r;
}
__device__ __forceinline__ float bf2f(unsigned short h) {
  return __builtin_bit_cast(float, (unsigned)h << 16);
}
__device__ __forceinline__ unsigned pack2(unsigned short a, unsigned short b) {
  return (unsigned)a | ((unsigned)b << 16);
}

__device__ __forceinline__ void gld_lds16(const void* g, void* l) {
  __builtin_amdgcn_global_load_lds(
      (const __attribute__((address_space(1))) unsigned int*)g,
      (__attribute__((address_space(3))) unsigned int*)l, 16, 0, 0);
}

#define SCHED0() __builtin_amdgcn_sched_barrier(0)
#define NTBAR() do { SCHED0(); __builtin_amdgcn_s_barrier(); SCHED0(); } while (0)
#define VMW(N) do { asm volatile("s_waitcnt vmcnt(" #N ")" ::: "memory"); SCHED0(); } while (0)
#define LGKM0() do { asm volatile("s_waitcnt lgkmcnt(0)" ::: "memory"); SCHED0(); } while (0)
#define MFMA16(a, b, c) __builtin_amdgcn_mfma_f32_16x16x32_bf16(a, b, c, 0, 0, 0)

// split 8 fp32 -> hi/lo bf16, store as uint4 pair (ds_write_b128)
__device__ __forceinline__ void split8_store(float4 v0, float4 v1,
                                             unsigned short* Hdst,
                                             unsigned short* Ldst) {
  float f[8] = {v0.x, v0.y, v0.z, v0.w, v1.x, v1.y, v1.z, v1.w};
  unsigned short hh[8], ll[8];
#pragma unroll
  for (int i = 0; i < 8; ++i) {
    hh[i] = f2bf(f[i]);
    ll[i] = f2bf(f[i] - bf2f(hh[i]));
  }
  *reinterpret_cast<uint4*>(Hdst) = make_uint4(pack2(hh[0], hh[1]), pack2(hh[2], hh[3]),
                                               pack2(hh[4], hh[5]), pack2(hh[6], hh[7]));
  *reinterpret_cast<uint4*>(Ldst) = make_uint4(pack2(ll[0], ll[1]), pack2(ll[2], ll[3]),
                                               pack2(ll[4], ll[5]), pack2(ll[6], ll[7]));
}

// -------- QB prep: Th/Tl[d][k] = split-bf16 of [Qm | Km] column d --------
__global__ __launch_bounds__(256) void qkm_split(const float* __restrict__ Qm,
                                                 const float* __restrict__ Km,
                                                 unsigned short* __restrict__ Th,
                                                 unsigned short* __restrict__ Tl) {
  __shared__ float lt[64][65];
  int k0 = blockIdx.x * 64;
  int half = blockIdx.y;
  const float* M = half ? Km : Qm;
  int t = threadIdx.x;
  int cl = (t & 15) * 4;
  int rl = t >> 4;
#pragma unroll
  for (int rr = 0; rr < 4; ++rr) {
    int r = rl + rr * 16;
    float4 v = *reinterpret_cast<const float4*>(&M[(long)(k0 + r) * 64 + cl]);
    lt[cl + 0][r] = v.x;
    lt[cl + 1][r] = v.y;
    lt[cl + 2][r] = v.z;
    lt[cl + 3][r] = v.w;
  }
  __syncthreads();
#pragma unroll
  for (int rr = 0; rr < 4; ++rr) {
    int c = rl + rr * 16;
    unsigned short h[4], lo[4];
#pragma unroll
    for (int i = 0; i < 4; ++i) {
      float f = lt[c][cl + i];
      h[i] = f2bf(f);
      lo[i] = f2bf(f - bf2f(h[i]));
    }
    *reinterpret_cast<uint2*>(&Th[(long)(half * 64 + c) * 1024 + k0 + cl]) =
        make_uint2(pack2(h[0], h[1]), pack2(h[2], h[3]));
    *reinterpret_cast<uint2*>(&Tl[(long)(half * 64 + c) * 1024 + k0 + cl]) =
        make_uint2(pack2(lo[0], lo[1]), pack2(lo[2], lo[3]));
  }
}

// -------- K1: qk split-bf16 out + fused x-transpose (xbT) --------------------
// qkh/qkl[row][128 d] = split-bf16 of x-row . [Qm|Km] col d.
// xbT[b][n][c] = bf16(x[b][c][n]) written back from the staged Xh tiles.
__global__ __launch_bounds__(256) void k1_mfma(const float* __restrict__ x,
                                               const unsigned short* __restrict__ Th,
                                               const unsigned short* __restrict__ Tl,
                                               unsigned short* __restrict__ qkh,
                                               unsigned short* __restrict__ qkl,
                                               unsigned short* __restrict__ xbT) {
  __shared__ unsigned short Dh[2][128 * 32];
  __shared__ unsigned short Dl[2][128 * 32];
  __shared__ unsigned short Xh[2][64 * 32];
  __shared__ unsigned short Xl[2][64 * 32];
  const int t = threadIdx.x;
  const int l = t & 63;
  const int w = t >> 6;
  const int wr = w >> 1, wc = w & 1;
  const long mBase = (long)blockIdx.x * 64;
  const int b = blockIdx.x >> 3;
  const int cBase = (blockIdx.x & 7) * 64;

  f32x4 acc[4][2];
#pragma unroll
  for (int m = 0; m < 4; ++m)
#pragma unroll
    for (int n = 0; n < 2; ++n) acc[m][n] = (f32x4){0.f, 0.f, 0.f, 0.f};

  const int xrow_l = t >> 2;
  const int kslot = t & 3;
  const int xsl = kslot ^ ((t >> 3) & 3);
  const int srcslot = (l & 3) ^ ((l >> 3) & 3);
  const int frag_off = (l & 15) * 32 + ((((l >> 4) ^ (l >> 1)) & 3) * 8);
  const float* xrow = x + (mBase + xrow_l) * 1024;

#define K1_STAGE_B(k0, p)                                                     \
  {                                                                           \
    _Pragma("unroll") for (int c = 0; c < 2; ++c) {                           \
      int ch = c * 4 + w;                                                     \
      int row = ch * 16 + (l >> 2);                                           \
      gld_lds16(Th + (long)row * 1024 + (k0) + srcslot * 8, &Dh[p][ch * 512]);\
      gld_lds16(Tl + (long)row * 1024 + (k0) + srcslot * 8, &Dl[p][ch * 512]);\
    }                                                                         \
  }

#define K1_COMPUTE(p)                                                         \
  {                                                                           \
    bf16x8 dh[4], dl[4], xh[2], xl[2];                                        \
    _Pragma("unroll") for (int m = 0; m < 4; ++m) {                           \
      dh[m] = *reinterpret_cast<const bf16x8*>(&Dh[p][(wr * 64 + m * 16) * 32 + frag_off]); \
      dl[m] = *reinterpret_cast<const bf16x8*>(&Dl[p][(wr * 64 + m * 16) * 32 + frag_off]); \
    }                                                                         \
    _Pragma("unroll") for (int n = 0; n < 2; ++n) {                           \
      xh[n] = *reinterpret_cast<const bf16x8*>(&Xh[p][(wc * 32 + n * 16) * 32 + frag_off]); \
      xl[n] = *reinterpret_cast<const bf16x8*>(&Xl[p][(wc * 32 + n * 16) * 32 + frag_off]); \
    }                                                                         \
    _Pragma("unroll") for (int m = 0; m < 4; ++m)                             \
        _Pragma("unroll") for (int n = 0; n < 2; ++n) {                       \
      acc[m][n] = MFMA16(dh[m], xh[n], acc[m][n]);                            \
      acc[m][n] = MFMA16(dh[m], xl[n], acc[m][n]);                            \
      acc[m][n] = MFMA16(dl[m], xh[n], acc[m][n]);                            \
    }                                                                         \
  }

  // read the bf16(x) tile back from Xh[p] (transposed) and store coalesced to xbT
#define K1_WRITEBACK(p, kk)                                                   \
  {                                                                           \
    int n_loc = t >> 3;                                                       \
    int c0w = (t & 7) * 8;                                                    \
    unsigned short vv[8];                                                     \
    _Pragma("unroll") for (int i2 = 0; i2 < 8; ++i2) {                        \
      int r = c0w + i2;                                                       \
      int sl2 = (n_loc >> 3) ^ ((r >> 1) & 3);                                \
      vv[i2] = Xh[p][r * 32 + sl2 * 8 + (n_loc & 7)];                         \
    }                                                                         \
    *reinterpret_cast<uint4*>(                                                \
        &xbT[(long)b * 524288 + (long)((kk) + n_loc) * 512 + cBase + c0w]) =  \
        make_uint4(pack2(vv[0], vv[1]), pack2(vv[2], vv[3]),                  \
                   pack2(vv[4], vv[5]), pack2(vv[6], vv[7]));                 \
  }

  {
    float4 p0 = *reinterpret_cast<const float4*>(&xrow[kslot * 8]);
    float4 p1 = *reinterpret_cast<const float4*>(&xrow[kslot * 8 + 4]);
    K1_STAGE_B(0, 0);
    split8_store(p0, p1, &Xh[0][xrow_l * 32 + xsl * 8], &Xl[0][xrow_l * 32 + xsl * 8]);
  }

  for (int k0 = 0; k0 < 1024; k0 += 64) {
    __syncthreads();
    float4 na0 = *reinterpret_cast<const float4*>(&xrow[k0 + 32 + kslot * 8]);
    float4 na1 = *reinterpret_cast<const float4*>(&xrow[k0 + 32 + kslot * 8 + 4]);
    K1_STAGE_B(k0 + 32, 1);
    K1_COMPUTE(0);
    split8_store(na0, na1, &Xh[1][xrow_l * 32 + xsl * 8], &Xl[1][xrow_l * 32 + xsl * 8]);
    K1_WRITEBACK(0, k0);
    __syncthreads();
    if (k0 + 64 < 1024) {
      float4 nb0 = *reinterpret_cast<const float4*>(&xrow[k0 + 64 + kslot * 8]);
      float4 nb1 = *reinterpret_cast<const float4*>(&xrow[k0 + 64 + kslot * 8 + 4]);
      K1_STAGE_B(k0 + 64, 0);
      K1_COMPUTE(1);
      split8_store(nb0, nb1, &Xh[0][xrow_l * 32 + xsl * 8], &Xl[0][xrow_l * 32 + xsl * 8]);
      K1_WRITEBACK(1, k0 + 32);
    } else {
      K1_COMPUTE(1);
      K1_WRITEBACK(1, k0 + 32);
    }
  }

#pragma unroll
  for (int m = 0; m < 4; ++m)
#pragma unroll
    for (int n = 0; n < 2; ++n) {
      int d0 = wr * 64 + m * 16 + (l >> 4) * 4;
      long xr = mBase + wc * 32 + n * 16 + (l & 15);
      unsigned short h4[4], l4[4];
#pragma unroll
      for (int reg = 0; reg < 4; ++reg) {
        float v = acc[m][n][reg];
        h4[reg] = f2bf(v);
        l4[reg] = f2bf(v - bf2f(h4[reg]));
      }
      *reinterpret_cast<uint2*>(&qkh[xr * 128 + d0]) =
          make_uint2(pack2(h4[0], h4[1]), pack2(h4[2], h4[3]));
      *reinterpret_cast<uint2*>(&qkl[xr * 128 + d0]) =
          make_uint2(pack2(l4[0], l4[1]), pack2(l4[2], l4[3]));
    }
#undef K1_STAGE_B
#undef K1_COMPUTE
#undef K1_WRITEBACK
}

// -------- K2a: st[b,j,i] = exp(sigmoid(q_i . k_j)), split-bf16 MFMA -----------
// Stages pre-split qkh/qkl via global_load_lds (lane-linear dest, swizzled src).
__global__ __launch_bounds__(256) void k2a_mfma(const unsigned short* __restrict__ qkh,
                                                const unsigned short* __restrict__ qkl,
                                                unsigned short* __restrict__ st) {
  __shared__ unsigned short Ah[128 * 64];
  __shared__ unsigned short Al[128 * 64];
  __shared__ unsigned short Bh[128 * 64];
  __shared__ unsigned short Bl[128 * 64];
  const int t = threadIdx.x;
  const int l = t & 63;
  const int w = t >> 6;
  const int wr = w >> 1, wc = w & 1;

  const int cpx = gridDim.x >> 3;
  const int orig = blockIdx.x;
  const int lw = (orig & 7) * cpx + (orig >> 3);
  const int b = lw >> 4;
  const int tile = lw & 15;
  const int iBase = (tile >> 2) * 128;
  const int jBase = (tile & 3) * 128;
  const long bq = (long)b * 512;

  // staging: lane l -> row rb + (l>>3), lds slot l&7; global slot sg = (l&7)^(l>>3)
  const int sg = (l & 7) ^ (l >> 3);
#pragma unroll
  for (int c4 = 0; c4 < 4; ++c4) {
    int rb = w * 32 + c4 * 8;
    long rowA = bq + iBase + rb + (l >> 3);
    long rowB = bq + jBase + rb + (l >> 3);
    gld_lds16(qkh + rowA * 128 + sg * 8, &Ah[rb * 64]);
    gld_lds16(qkl + rowA * 128 + sg * 8, &Al[rb * 64]);
    gld_lds16(qkh + rowB * 128 + 64 + sg * 8, &Bh[rb * 64]);
    gld_lds16(qkl + rowB * 128 + 64 + sg * 8, &Bl[rb * 64]);
  }
  __syncthreads();

  f32x4 acc[4][4];
#pragma unroll
  for (int m = 0; m < 4; ++m)
#pragma unroll
    for (int n = 0; n < 4; ++n) acc[m][n] = (f32x4){0.f, 0.f, 0.f, 0.f};

#pragma unroll
  for (int ks = 0; ks < 2; ++ks) {
    bf16x8 ah[4], al4[4], bh[4], bl4[4];
#pragma unroll
    for (int m = 0; m < 4; ++m) {
      int row = wr * 64 + m * 16 + (l & 15);
      int off = row * 64 + ((ks * 4 + (l >> 4)) ^ (row & 7)) * 8;
      ah[m] = *reinterpret_cast<const bf16x8*>(&Ah[off]);
      al4[m] = *reinterpret_cast<const bf16x8*>(&Al[off]);
    }
#pragma unroll
    for (int n = 0; n < 4; ++n) {
      int row = wc * 64 + n * 16 + (l & 15);
      int off = row * 64 + ((ks * 4 + (l >> 4)) ^ (row & 7)) * 8;
      bh[n] = *reinterpret_cast<const bf16x8*>(&Bh[off]);
      bl4[n] = *reinterpret_cast<const bf16x8*>(&Bl[off]);
    }
#pragma unroll
    for (int m = 0; m < 4; ++m)
#pragma unroll
      for (int n = 0; n < 4; ++n) {
        acc[m][n] = MFMA16(ah[m], bh[n], acc[m][n]);
        acc[m][n] = MFMA16(ah[m], bl4[n], acc[m][n]);
        acc[m][n] = MFMA16(al4[m], bh[n], acc[m][n]);
      }
  }

  unsigned short* sb = st + (long)b * 512 * 512;
#pragma unroll
  for (int m = 0; m < 4; ++m)
#pragma unroll
    for (int n = 0; n < 4; ++n) {
      int i0 = iBase + wr * 64 + m * 16 + (l >> 4) * 4;
      int j = jBase + wc * 64 + n * 16 + (l & 15);
      unsigned short p[4];
#pragma unroll
      for (int reg = 0; reg < 4; ++reg) {
        float sg2 = 1.0f / (1.0f + __expf(-acc[m][n][reg]));
        p[reg] = f2bf(__expf(sg2));
      }
      *reinterpret_cast<uint2*>(&sb[(long)j * 512 + i0]) = *reinterpret_cast<uint2*>(p);
    }
}

// -------- K2b: per-row (j) sums of st -> rsum = 1/sum, attbias = (st.bias)/sum ----
__global__ __launch_bounds__(256) void k2b_rsum(const unsigned short* __restrict__ st,
                                                const float* __restrict__ bias,
                                                float* __restrict__ rsum,
                                                float* __restrict__ attbias) {
  int jg = blockIdx.x * 4 + (threadIdx.x >> 6);
  int l = threadIdx.x & 63;
  const unsigned short* row = st + (long)jg * 512 + l * 8;
  ushort4 u0 = *reinterpret_cast<const ushort4*>(row);
  ushort4 u1 = *reinterpret_cast<const ushort4*>(row + 4);
  float4 b0 = *reinterpret_cast<const float4*>(&bias[l * 8]);
  float4 b1 = *reinterpret_cast<const float4*>(&bias[l * 8 + 4]);
  float f0 = bf2f(u0.x), f1 = bf2f(u0.y), f2 = bf2f(u0.z), f3 = bf2f(u0.w);
  float f4 = bf2f(u1.x), f5 = bf2f(u1.y), f6 = bf2f(u1.z), f7 = bf2f(u1.w);
  float sum = (f0 + f1) + (f2 + f3) + ((f4 + f5) + (f6 + f7));
  float sumb = f0 * b0.x + f1 * b0.y + f2 * b0.z + f3 * b0.w +
               f4 * b1.x + f5 * b1.y + f6 * b1.z + f7 * b1.w;
#pragma unroll
  for (int off = 32; off > 0; off >>= 1) {
    sum += __shfl_down(sum, off);
    sumb += __shfl_down(sumb, off);
  }
  if (l == 0) {
    float r = 1.0f / sum;
    rsum[jg] = r;
    attbias[jg] = sumb * r;
  }
}

// -------- transpose + fp32->bf16 convert: out[c][r] = bf16(in[r][c]) --------
__global__ __launch_bounds__(256) void transpose_conv(const float* __restrict__ in,
                                                      unsigned short* __restrict__ out,
                                                      int inRows, int inCols,
                                                      long inBatch, long outBatch) {
  __shared__ unsigned short lt[64][65];
  int b = blockIdx.z;
  int r0 = blockIdx.y * 64;
  int c0 = blockIdx.x * 64;
  const float* I = in + (long)b * inBatch;
  unsigned short* O = out + (long)b * outBatch;
  int t = threadIdx.x;
  int cl = (t & 15) * 4;
  int rl = t >> 4;
#pragma unroll
  for (int rr = 0; rr < 4; ++rr) {
    int r = rl + rr * 16;
    float4 v = *reinterpret_cast<const float4*>(&I[(long)(r0 + r) * inCols + c0 + cl]);
    lt[cl + 0][r] = f2bf(v.x);
    lt[cl + 1][r] = f2bf(v.y);
    lt[cl + 2][r] = f2bf(v.z);
    lt[cl + 3][r] = f2bf(v.w);
  }
  __syncthreads();
#pragma unroll
  for (int rr = 0; rr < 4; ++rr) {
    int c = rl + rr * 16;
    unsigned short v[4] = {lt[c][cl], lt[c][cl + 1], lt[c][cl + 2], lt[c][cl + 3]};
    *reinterpret_cast<uint2*>(&O[(long)(c0 + c) * inRows + r0 + cl]) =
        *reinterpret_cast<uint2*>(&v[0]);
  }
}

// ======== 256x256 bf16 MFMA GEMM, BK=64, 8 waves, 8-PHASE schedule (m201) ========
template <int MODE>
__global__ __launch_bounds__(512) void mfma_nt256(const unsigned short* __restrict__ Abase,
                                                  const unsigned short* __restrict__ Bbase,
                                                  const float* __restrict__ rowscale,
                                                  unsigned short* __restrict__ Wout,
                                                  float* __restrict__ Fout) {
  __shared__ unsigned short As[2][256 * 64];
  __shared__ unsigned short Bs[2][256 * 64];
  const int t = threadIdx.x;
  const int l = t & 63;
  const int w = t >> 6;          // 0..7
  const int wr = w >> 2;         // 0..1  (M: 2 x 128)
  const int wc = w & 3;          // 0..3  (N: 4 x 64)

  const int cpx = gridDim.x >> 3;
  const int orig = blockIdx.x;
  const int lw = (orig & 7) * cpx + (orig >> 3);
  const int TPB_SH = (MODE == 0) ? 2 : 3;
  const int b = lw >> TPB_SH;
  const int tile = lw & ((1 << TPB_SH) - 1);
  const int mBase = (tile >> 1) * 256;
  const int nBase = (tile & 1) * 256;

  const unsigned short* Ag = Abase + ((MODE == 0) ? 0L : (long)b * (1024 * 512)) + (long)mBase * 512;
  const unsigned short* Bg = Bbase + (long)b * (512 * 512) + (long)nBase * 512;

  f32x4 acc[8][4];
#pragma unroll
  for (int m = 0; m < 8; ++m)
#pragma unroll
    for (int n = 0; n < 4; ++n) acc[m][n] = (f32x4){0.f, 0.f, 0.f, 0.f};

  const int srcslot = (l & 7) ^ (l >> 3);
  const int so0 = ((l >> 4) ^ (l & 7)) * 8;
  const int so1 = ((4 + (l >> 4)) ^ (l & 7)) * 8;

#define STG_A(p, tt, pr)                                                       \
  gld_lds16(Ag + (long)((pr) * 64 + w * 8 + (l >> 3)) * 512 + (tt) * 64 + srcslot * 8, \
            &As[p][((pr) * 64 + w * 8) * 64]);
#define STG_B(p, tt, pr)                                                       \
  gld_lds16(Bg + (long)((pr) * 64 + w * 8 + (l >> 3)) * 512 + (tt) * 64 + srcslot * 8, \
            &Bs[p][((pr) * 64 + w * 8) * 64]);

#define PHASE(p, q, STAGE_STMT, VMSTMT)                                        \
  {                                                                            \
    bf16x8 a00 = *reinterpret_cast<const bf16x8*>(                             \
        &As[p][(wr * 128 + (2 * (q)) * 16 + (l & 15)) * 64 + so0]);            \
    bf16x8 a01 = *reinterpret_cast<const bf16x8*>(                             \
        &As[p][(wr * 128 + (2 * (q)) * 16 + (l & 15)) * 64 + so1]);            \
    bf16x8 a10 = *reinterpret_cast<const bf16x8*>(                             \
        &As[p][(wr * 128 + (2 * (q) + 1) * 16 + (l & 15)) * 64 + so0]);        \
    bf16x8 a11 = *reinterpret_cast<const bf16x8*>(                             \
        &As[p][(wr * 128 + (2 * (q) + 1) * 16 + (l & 15)) * 64 + so1]);        \
    if ((q) == 0) {                                                            \
      _Pragma("unroll") for (int n = 0; n < 4; ++n) {                          \
        bfr0[n] = *reinterpret_cast<const bf16x8*>(                            \
            &Bs[p][(wc * 64 + n * 16 + (l & 15)) * 64 + so0]);                 \
        bfr1[n] = *reinterpret_cast<const bf16x8*>(                            \
            &Bs[p][(wc * 64 + n * 16 + (l & 15)) * 64 + so1]);                 \
      }                                                                        \
    }                                                                          \
    STAGE_STMT;                                                                \
    SCHED0();                                                                  \
    __builtin_amdgcn_s_barrier();                                              \
    LGKM0();                                                                   \
    __builtin_amdgcn_s_setprio(1);                                             \
    _Pragma("unroll") for (int n = 0; n < 4; ++n) {                            \
      acc[2 * (q)][n] = MFMA16(a00, bfr0[n], acc[2 * (q)][n]);                 \
      acc[2 * (q)][n] = MFMA16(a01, bfr1[n], acc[2 * (q)][n]);                 \
      acc[2 * (q) + 1][n] = MFMA16(a10, bfr0[n], acc[2 * (q) + 1][n]);         \
      acc[2 * (q) + 1][n] = MFMA16(a11, bfr1[n], acc[2 * (q) + 1][n]);         \
    }                                                                          \
    __builtin_amdgcn_s_setprio(0);                                             \
    VMSTMT;                                                                    \
    NTBAR();                                                                   \
  }

  bf16x8 bfr0[4], bfr1[4];

  // prologue: buf0 <- tile0 (8 loads), buf1 <- B0,B1,Ha of tile1 (6 loads)
  STG_A(0, 0, 0); STG_A(0, 0, 1); STG_A(0, 0, 2); STG_A(0, 0, 3);
  STG_B(0, 0, 0); STG_B(0, 0, 1); STG_B(0, 0, 2); STG_B(0, 0, 3);
  STG_B(1, 1, 0); STG_B(1, 1, 1); STG_B(1, 1, 2); STG_B(1, 1, 3);
  STG_A(1, 1, 0); STG_A(1, 1, 2);
  VMW(6);
  NTBAR();

  for (int it = 0; it < 4; ++it) {
    const int t1 = 2 * it + 1;
    const int t2 = (2 * it + 2 < 8) ? 2 * it + 2 : 7;
    const int t3 = (2 * it + 3 < 8) ? 2 * it + 3 : 7;
    PHASE(0, 0, { STG_A(1, t1, 1); STG_A(1, t1, 3); }, );
    PHASE(0, 1, { STG_B(0, t2, 0); STG_B(0, t2, 1); }, VMW(10));
    PHASE(0, 2, { STG_B(0, t2, 2); STG_B(0, t2, 3); }, );
    PHASE(0, 3, { STG_A(0, t2, 0); STG_A(0, t2, 2); }, VMW(8));
    PHASE(1, 0, { STG_A(0, t2, 1); STG_A(0, t2, 3); }, );
    PHASE(1, 1, { STG_B(1, t3, 0); STG_B(1, t3, 1); }, VMW(10));
    PHASE(1, 2, { STG_B(1, t3, 2); STG_B(1, t3, 3); }, );
    PHASE(1, 3, { STG_A(1, t3, 0); STG_A(1, t3, 2); }, VMW(8));
  }
#undef PHASE
#undef STG_A
#undef STG_B

  if (MODE == 0) {
    unsigned short* W = Wout + (long)b * (512 * 512);
#pragma unroll
    for (int n = 0; n < 4; ++n) {
      int j = nBase + wc * 64 + n * 16 + (l & 15);
      float rs = rowscale[b * 512 + j];
#pragma unroll
      for (int m = 0; m < 8; ++m) {
        int c0 = mBase + wr * 128 + m * 16 + (l >> 4) * 4;
        unsigned short p[4];
#pragma unroll
        for (int reg = 0; reg < 4; ++reg) p[reg] = f2bf(acc[m][n][reg] * rs);
        *reinterpret_cast<uint2*>(&W[(long)j * 512 + c0]) = *reinterpret_cast<uint2*>(p);
      }
    }
  } else {
    float* O = Fout + (long)b * (512 * 1024);
#pragma unroll
    for (int n = 0; n < 4; ++n) {
      int j = nBase + wc * 64 + n * 16 + (l & 15);
      float ab = rowscale[b * 512 + j];
#pragma unroll
      for (int m = 0; m < 8; ++m) {
        int n0 = mBase + wr * 128 + m * 16 + (l >> 4) * 4;
        *reinterpret_cast<float4*>(&O[(long)j * 1024 + n0]) =
            make_float4(acc[m][n][0] + ab, acc[m][n][1] + ab,
                        acc[m][n][2] + ab, acc[m][n][3] + ab);
      }
    }
  }
}

extern "C" void kernel_launch(void* const* d_in, const int* in_sizes, int n_in,
                              void* d_out, int out_size, void* d_ws, size_t ws_size,
                              hipStream_t stream) {
  const float* x  = (const float*)d_in[0];
  const float* Qm = (const float*)d_in[1];
  const float* Km = (const float*)d_in[2];
  const float* vw = (const float*)d_in[3];
  const float* vb = (const float*)d_in[4];
  float* out = (float*)d_out;

  float* ws = (float*)d_ws;
  unsigned short* qkh  = (unsigned short*)ws;                         // 4,194,304 ush (spans 2,097,152 f)
  unsigned short* qkl  = qkh + 4194304;                               // 4,194,304 ush (spans 2,097,152 f)
  unsigned short* st   = (unsigned short*)(ws + 4194304);             // spans 8,388,608 f
  unsigned short* weff = (unsigned short*)(ws + 4194304 + 8388608);   // spans 8,388,608 f
  unsigned short* xbT  = (unsigned short*)(ws + 4194304 + 16777216);  // spans 16,777,216 f
  unsigned short* vwT  = (unsigned short*)(ws + 4194304 + 33554432);  // spans 131,072 f
  unsigned short* qkTh = (unsigned short*)(ws + 4194304 + 33554432 + 131072);  // 65,536 f
  unsigned short* qkTl = qkTh + 131072;                               // 65,536 f
  float* rsum    = ws + 4194304 + 33554432 + 131072 + 131072;         // 32,768 f
  float* attbias = rsum + 32768;                                      // 32,768 f

  // T2: vwT[c][i] = bf16(vw[i][c])
  transpose_conv<<<dim3(8, 8, 1), 256, 0, stream>>>(vw, vwT, 512, 512, 0L, 0L);
  // T3: split-transposed [Qm|Km] -> qkTh/qkTl [128][1024]
  qkm_split<<<dim3(16, 2), 256, 0, stream>>>(Qm, Km, qkTh, qkTl);
  // K1: qkh/qkl = split(x @ [Qm|Km]) + fused xbT transpose (T1 eliminated)
  k1_mfma<<<512, 256, 0, stream>>>(x, qkTh, qkTl, qkh, qkl, xbT);
  // K2a: st[b,j,i] = exp(sigmoid(q_i . k_j)), gld_lds staging of qkh/qkl
  k2a_mfma<<<1024, 256, 0, stream>>>(qkh, qkl, st);
  // K2b: rsum, attbias
  k2b_rsum<<<8192, 256, 0, stream>>>(st, vb, rsum, attbias);
  // K3: weff = diag(rsum) . st . Vw   (A=vwT, B=st), 4 tiles/b
  mfma_nt256<0><<<256, 512, 0, stream>>>(vwT, st, rsum, weff, nullptr);
  // K4: out = weff . xf + attbias     (A=xbT, B=weff), 8 tiles/b
  mfma_nt256<1><<<512, 512, 0, stream>>>(xbT, weff, attbias, nullptr, out);
}

// Round 10
// 201.312 us; speedup vs baseline: 1.1775x; 1.0173x over previous
//
#include <hip/hip_runtime.h>

#define BK 32

typedef __attribute__((ext_vector_type(8))) short bf16x8;
typedef __attribute__((ext_vector_type(4))) float f32x4;

__device__ __forceinline__ unsigned short f2bf(float f) {
  unsigned u = __builtin_bit_cast(unsigned, f);
  unsigned r = (u + 0x7FFFu + ((u >> 16) & 1u)) >> 16;
  return (unsigned short)r;
}
__device__ __forceinline__ float bf2f(unsigned short h) {
  return __builtin_bit_cast(float, (unsigned)h << 16);
}
__device__ __forceinline__ unsigned pack2(unsigned short a, unsigned short b) {
  return (unsigned)a | ((unsigned)b << 16);
}

__device__ __forceinline__ void gld_lds16(const void* g, void* l) {
  __builtin_amdgcn_global_load_lds(
      (const __attribute__((address_space(1))) unsigned int*)g,
      (__attribute__((address_space(3))) unsigned int*)l, 16, 0, 0);
}

#define SCHED0() __builtin_amdgcn_sched_barrier(0)
#define NTBAR() do { SCHED0(); __builtin_amdgcn_s_barrier(); SCHED0(); } while (0)
#define VMW(N) do { asm volatile("s_waitcnt vmcnt(" #N ")" ::: "memory"); SCHED0(); } while (0)
#define LGKM0() do { asm volatile("s_waitcnt lgkmcnt(0)" ::: "memory"); SCHED0(); } while (0)
#define MFMA16(a, b, c) __builtin_amdgcn_mfma_f32_16x16x32_bf16(a, b, c, 0, 0, 0)

// split 8 fp32 -> hi/lo bf16, store as uint4 pair (ds_write_b128)
__device__ __forceinline__ void split8_store(float4 v0, float4 v1,
                                             unsigned short* Hdst,
                                             unsigned short* Ldst) {
  float f[8] = {v0.x, v0.y, v0.z, v0.w, v1.x, v1.y, v1.z, v1.w};
  unsigned short hh[8], ll[8];
#pragma unroll
  for (int i = 0; i < 8; ++i) {
    hh[i] = f2bf(f[i]);
    ll[i] = f2bf(f[i] - bf2f(hh[i]));
  }
  *reinterpret_cast<uint4*>(Hdst) = make_uint4(pack2(hh[0], hh[1]), pack2(hh[2], hh[3]),
                                               pack2(hh[4], hh[5]), pack2(hh[6], hh[7]));
  *reinterpret_cast<uint4*>(Ldst) = make_uint4(pack2(ll[0], ll[1]), pack2(ll[2], ll[3]),
                                               pack2(ll[4], ll[5]), pack2(ll[6], ll[7]));
}

// split + additionally scatter hi-bf16 into the transpose buffer Tt[k][c-swizzled]
__device__ __forceinline__ void split8_store_tt(float4 v0, float4 v1,
                                                unsigned short* Hdst,
                                                unsigned short* Ldst,
                                                unsigned short* Ttb,
                                                int kslot, int c) {
  float f[8] = {v0.x, v0.y, v0.z, v0.w, v1.x, v1.y, v1.z, v1.w};
  unsigned short hh[8], ll[8];
#pragma unroll
  for (int i = 0; i < 8; ++i) {
    hh[i] = f2bf(f[i]);
    ll[i] = f2bf(f[i] - bf2f(hh[i]));
  }
  *reinterpret_cast<uint4*>(Hdst) = make_uint4(pack2(hh[0], hh[1]), pack2(hh[2], hh[3]),
                                               pack2(hh[4], hh[5]), pack2(hh[6], hh[7]));
  *reinterpret_cast<uint4*>(Ldst) = make_uint4(pack2(ll[0], ll[1]), pack2(ll[2], ll[3]),
                                               pack2(ll[4], ll[5]), pack2(ll[6], ll[7]));
#pragma unroll
  for (int i = 0; i < 8; ++i) {
    int g = ((c >> 3) ^ i ^ kslot) & 7;  // (c>>3) ^ (k&7) ^ (k>>3), k = kslot*8+i
    Ttb[(kslot * 8 + i) * 72 + g * 8 + (c & 7)] = hh[i];
  }
}

// -------- QB prep: Th/Tl[d][k] = split-bf16 of [Qm | Km] column d --------
__global__ __launch_bounds__(256) void qkm_split(const float* __restrict__ Qm,
                                                 const float* __restrict__ Km,
                                                 unsigned short* __restrict__ Th,
                                                 unsigned short* __restrict__ Tl) {
  __shared__ float lt[64][65];
  int k0 = blockIdx.x * 64;
  int half = blockIdx.y;
  const float* M = half ? Km : Qm;
  int t = threadIdx.x;
  int cl = (t & 15) * 4;
  int rl = t >> 4;
#pragma unroll
  for (int rr = 0; rr < 4; ++rr) {
    int r = rl + rr * 16;
    float4 v = *reinterpret_cast<const float4*>(&M[(long)(k0 + r) * 64 + cl]);
    lt[cl + 0][r] = v.x;
    lt[cl + 1][r] = v.y;
    lt[cl + 2][r] = v.z;
    lt[cl + 3][r] = v.w;
  }
  __syncthreads();
#pragma unroll
  for (int rr = 0; rr < 4; ++rr) {
    int c = rl + rr * 16;
    unsigned short h[4], lo[4];
#pragma unroll
    for (int i = 0; i < 4; ++i) {
      float f = lt[c][cl + i];
      h[i] = f2bf(f);
      lo[i] = f2bf(f - bf2f(h[i]));
    }
    *reinterpret_cast<uint2*>(&Th[(long)(half * 64 + c) * 1024 + k0 + cl]) =
        make_uint2(pack2(h[0], h[1]), pack2(h[2], h[3]));
    *reinterpret_cast<uint2*>(&Tl[(long)(half * 64 + c) * 1024 + k0 + cl]) =
        make_uint2(pack2(lo[0], lo[1]), pack2(lo[2], lo[3]));
  }
}

// -------- K1: qk split-bf16 out + fused x-transpose (xbT) --------------------
// qkh/qkl[row][128 d] = split-bf16 of x-row . [Qm|Km] col d.
// xbT[b][n][c] = bf16(x[b][c][n]) via dedicated swizzled transpose buffer Tt.
__global__ __launch_bounds__(256) void k1_mfma(const float* __restrict__ x,
                                               const unsigned short* __restrict__ Th,
                                               const unsigned short* __restrict__ Tl,
                                               unsigned short* __restrict__ qkh,
                                               unsigned short* __restrict__ qkl,
                                               unsigned short* __restrict__ xbT) {
  __shared__ unsigned short Dh[2][128 * 32];
  __shared__ unsigned short Dl[2][128 * 32];
  __shared__ unsigned short Xh[2][64 * 32];
  __shared__ unsigned short Xl[2][64 * 32];
  __shared__ unsigned short Tt[2][32 * 72];
  const int t = threadIdx.x;
  const int l = t & 63;
  const int w = t >> 6;
  const int wr = w >> 1, wc = w & 1;
  const long mBase = (long)blockIdx.x * 64;
  const int b = blockIdx.x >> 3;
  const int cBase = (blockIdx.x & 7) * 64;

  f32x4 acc[4][2];
#pragma unroll
  for (int m = 0; m < 4; ++m)
#pragma unroll
    for (int n = 0; n < 2; ++n) acc[m][n] = (f32x4){0.f, 0.f, 0.f, 0.f};

  const int xrow_l = t >> 2;
  const int kslot = t & 3;
  const int xsl = kslot ^ ((t >> 3) & 3);
  const int srcslot = (l & 3) ^ ((l >> 3) & 3);
  const int frag_off = (l & 15) * 32 + ((((l >> 4) ^ (l >> 1)) & 3) * 8);
  const float* xrow = x + (mBase + xrow_l) * 1024;

#define K1_STAGE_B(k0, p)                                                     \
  {                                                                           \
    _Pragma("unroll") for (int c = 0; c < 2; ++c) {                           \
      int ch = c * 4 + w;                                                     \
      int row = ch * 16 + (l >> 2);                                           \
      gld_lds16(Th + (long)row * 1024 + (k0) + srcslot * 8, &Dh[p][ch * 512]);\
      gld_lds16(Tl + (long)row * 1024 + (k0) + srcslot * 8, &Dl[p][ch * 512]);\
    }                                                                         \
  }

#define K1_COMPUTE(p)                                                         \
  {                                                                           \
    bf16x8 dh[4], dl[4], xh[2], xl[2];                                        \
    _Pragma("unroll") for (int m = 0; m < 4; ++m) {                           \
      dh[m] = *reinterpret_cast<const bf16x8*>(&Dh[p][(wr * 64 + m * 16) * 32 + frag_off]); \
      dl[m] = *reinterpret_cast<const bf16x8*>(&Dl[p][(wr * 64 + m * 16) * 32 + frag_off]); \
    }                                                                         \
    _Pragma("unroll") for (int n = 0; n < 2; ++n) {                           \
      xh[n] = *reinterpret_cast<const bf16x8*>(&Xh[p][(wc * 32 + n * 16) * 32 + frag_off]); \
      xl[n] = *reinterpret_cast<const bf16x8*>(&Xl[p][(wc * 32 + n * 16) * 32 + frag_off]); \
    }                                                                         \
    _Pragma("unroll") for (int m = 0; m < 4; ++m)                             \
        _Pragma("unroll") for (int n = 0; n < 2; ++n) {                       \
      acc[m][n] = MFMA16(dh[m], xh[n], acc[m][n]);                            \
      acc[m][n] = MFMA16(dh[m], xl[n], acc[m][n]);                            \
      acc[m][n] = MFMA16(dl[m], xh[n], acc[m][n]);                            \
    }                                                                         \
  }

  // read one b128 row-slice from Tt[p] and store coalesced 16B to xbT
#define K1_WRITEBACK(p, kk)                                                   \
  {                                                                           \
    int n2 = t >> 3;                                                          \
    int g2 = t & 7;                                                           \
    int gs = (g2 ^ (n2 & 7) ^ (n2 >> 3)) & 7;                                 \
    uint4 vv = *reinterpret_cast<const uint4*>(&Tt[p][n2 * 72 + gs * 8]);     \
    *reinterpret_cast<uint4*>(                                                \
        &xbT[(long)b * 524288 + (long)((kk) + n2) * 512 + cBase + g2 * 8]) = vv; \
  }

  {
    float4 p0 = *reinterpret_cast<const float4*>(&xrow[kslot * 8]);
    float4 p1 = *reinterpret_cast<const float4*>(&xrow[kslot * 8 + 4]);
    K1_STAGE_B(0, 0);
    split8_store_tt(p0, p1, &Xh[0][xrow_l * 32 + xsl * 8], &Xl[0][xrow_l * 32 + xsl * 8],
                    Tt[0], kslot, xrow_l);
  }

  for (int k0 = 0; k0 < 1024; k0 += 64) {
    __syncthreads();
    float4 na0 = *reinterpret_cast<const float4*>(&xrow[k0 + 32 + kslot * 8]);
    float4 na1 = *reinterpret_cast<const float4*>(&xrow[k0 + 32 + kslot * 8 + 4]);
    K1_STAGE_B(k0 + 32, 1);
    K1_COMPUTE(0);
    split8_store_tt(na0, na1, &Xh[1][xrow_l * 32 + xsl * 8], &Xl[1][xrow_l * 32 + xsl * 8],
                    Tt[1], kslot, xrow_l);
    K1_WRITEBACK(0, k0);
    __syncthreads();
    if (k0 + 64 < 1024) {
      float4 nb0 = *reinterpret_cast<const float4*>(&xrow[k0 + 64 + kslot * 8]);
      float4 nb1 = *reinterpret_cast<const float4*>(&xrow[k0 + 64 + kslot * 8 + 4]);
      K1_STAGE_B(k0 + 64, 0);
      K1_COMPUTE(1);
      split8_store_tt(nb0, nb1, &Xh[0][xrow_l * 32 + xsl * 8], &Xl[0][xrow_l * 32 + xsl * 8],
                      Tt[0], kslot, xrow_l);
      K1_WRITEBACK(1, k0 + 32);
    } else {
      K1_COMPUTE(1);
      K1_WRITEBACK(1, k0 + 32);
    }
  }

#pragma unroll
  for (int m = 0; m < 4; ++m)
#pragma unroll
    for (int n = 0; n < 2; ++n) {
      int d0 = wr * 64 + m * 16 + (l >> 4) * 4;
      long xr = mBase + wc * 32 + n * 16 + (l & 15);
      unsigned short h4[4], l4[4];
#pragma unroll
      for (int reg = 0; reg < 4; ++reg) {
        float v = acc[m][n][reg];
        h4[reg] = f2bf(v);
        l4[reg] = f2bf(v - bf2f(h4[reg]));
      }
      *reinterpret_cast<uint2*>(&qkh[xr * 128 + d0]) =
          make_uint2(pack2(h4[0], h4[1]), pack2(h4[2], h4[3]));
      *reinterpret_cast<uint2*>(&qkl[xr * 128 + d0]) =
          make_uint2(pack2(l4[0], l4[1]), pack2(l4[2], l4[3]));
    }
#undef K1_STAGE_B
#undef K1_COMPUTE
#undef K1_WRITEBACK
}

// -------- K2a: st[b,j,i] = exp(sigmoid(q_i . k_j)), split-bf16 MFMA -----------
// Stages pre-split qkh/qkl via global_load_lds (lane-linear dest, swizzled src).
__global__ __launch_bounds__(256) void k2a_mfma(const unsigned short* __restrict__ qkh,
                                                const unsigned short* __restrict__ qkl,
                                                unsigned short* __restrict__ st) {
  __shared__ unsigned short Ah[128 * 64];
  __shared__ unsigned short Al[128 * 64];
  __shared__ unsigned short Bh[128 * 64];
  __shared__ unsigned short Bl[128 * 64];
  const int t = threadIdx.x;
  const int l = t & 63;
  const int w = t >> 6;
  const int wr = w >> 1, wc = w & 1;

  const int cpx = gridDim.x >> 3;
  const int orig = blockIdx.x;
  const int lw = (orig & 7) * cpx + (orig >> 3);
  const int b = lw >> 4;
  const int tile = lw & 15;
  const int iBase = (tile >> 2) * 128;
  const int jBase = (tile & 3) * 128;
  const long bq = (long)b * 512;

  const int sg = (l & 7) ^ (l >> 3);
#pragma unroll
  for (int c4 = 0; c4 < 4; ++c4) {
    int rb = w * 32 + c4 * 8;
    long rowA = bq + iBase + rb + (l >> 3);
    long rowB = bq + jBase + rb + (l >> 3);
    gld_lds16(qkh + rowA * 128 + sg * 8, &Ah[rb * 64]);
    gld_lds16(qkl + rowA * 128 + sg * 8, &Al[rb * 64]);
    gld_lds16(qkh + rowB * 128 + 64 + sg * 8, &Bh[rb * 64]);
    gld_lds16(qkl + rowB * 128 + 64 + sg * 8, &Bl[rb * 64]);
  }
  __syncthreads();

  f32x4 acc[4][4];
#pragma unroll
  for (int m = 0; m < 4; ++m)
#pragma unroll
    for (int n = 0; n < 4; ++n) acc[m][n] = (f32x4){0.f, 0.f, 0.f, 0.f};

#pragma unroll
  for (int ks = 0; ks < 2; ++ks) {
    bf16x8 ah[4], al4[4], bh[4], bl4[4];
#pragma unroll
    for (int m = 0; m < 4; ++m) {
      int row = wr * 64 + m * 16 + (l & 15);
      int off = row * 64 + ((ks * 4 + (l >> 4)) ^ (row & 7)) * 8;
      ah[m] = *reinterpret_cast<const bf16x8*>(&Ah[off]);
      al4[m] = *reinterpret_cast<const bf16x8*>(&Al[off]);
    }
#pragma unroll
    for (int n = 0; n < 4; ++n) {
      int row = wc * 64 + n * 16 + (l & 15);
      int off = row * 64 + ((ks * 4 + (l >> 4)) ^ (row & 7)) * 8;
      bh[n] = *reinterpret_cast<const bf16x8*>(&Bh[off]);
      bl4[n] = *reinterpret_cast<const bf16x8*>(&Bl[off]);
    }
#pragma unroll
    for (int m = 0; m < 4; ++m)
#pragma unroll
      for (int n = 0; n < 4; ++n) {
        acc[m][n] = MFMA16(ah[m], bh[n], acc[m][n]);
        acc[m][n] = MFMA16(ah[m], bl4[n], acc[m][n]);
        acc[m][n] = MFMA16(al4[m], bh[n], acc[m][n]);
      }
  }

  unsigned short* sb = st + (long)b * 512 * 512;
#pragma unroll
  for (int m = 0; m < 4; ++m)
#pragma unroll
    for (int n = 0; n < 4; ++n) {
      int i0 = iBase + wr * 64 + m * 16 + (l >> 4) * 4;
      int j = jBase + wc * 64 + n * 16 + (l & 15);
      unsigned short p[4];
#pragma unroll
      for (int reg = 0; reg < 4; ++reg) {
        float sg2 = 1.0f / (1.0f + __expf(-acc[m][n][reg]));
        p[reg] = f2bf(__expf(sg2));
      }
      *reinterpret_cast<uint2*>(&sb[(long)j * 512 + i0]) = *reinterpret_cast<uint2*>(p);
    }
}

// -------- K2b: per-row (j) sums of st -> rsum = 1/sum, attbias = (st.bias)/sum ----
__global__ __launch_bounds__(256) void k2b_rsum(const unsigned short* __restrict__ st,
                                                const float* __restrict__ bias,
                                                float* __restrict__ rsum,
                                                float* __restrict__ attbias) {
  int jg = blockIdx.x * 4 + (threadIdx.x >> 6);
  int l = threadIdx.x & 63;
  const unsigned short* row = st + (long)jg * 512 + l * 8;
  ushort4 u0 = *reinterpret_cast<const ushort4*>(row);
  ushort4 u1 = *reinterpret_cast<const ushort4*>(row + 4);
  float4 b0 = *reinterpret_cast<const float4*>(&bias[l * 8]);
  float4 b1 = *reinterpret_cast<const float4*>(&bias[l * 8 + 4]);
  float f0 = bf2f(u0.x), f1 = bf2f(u0.y), f2 = bf2f(u0.z), f3 = bf2f(u0.w);
  float f4 = bf2f(u1.x), f5 = bf2f(u1.y), f6 = bf2f(u1.z), f7 = bf2f(u1.w);
  float sum = (f0 + f1) + (f2 + f3) + ((f4 + f5) + (f6 + f7));
  float sumb = f0 * b0.x + f1 * b0.y + f2 * b0.z + f3 * b0.w +
               f4 * b1.x + f5 * b1.y + f6 * b1.z + f7 * b1.w;
#pragma unroll
  for (int off = 32; off > 0; off >>= 1) {
    sum += __shfl_down(sum, off);
    sumb += __shfl_down(sumb, off);
  }
  if (l == 0) {
    float r = 1.0f / sum;
    rsum[jg] = r;
    attbias[jg] = sumb * r;
  }
}

// -------- transpose + fp32->bf16 convert: out[c][r] = bf16(in[r][c]) --------
__global__ __launch_bounds__(256) void transpose_conv(const float* __restrict__ in,
                                                      unsigned short* __restrict__ out,
                                                      int inRows, int inCols,
                                                      long inBatch, long outBatch) {
  __shared__ unsigned short lt[64][65];
  int b = blockIdx.z;
  int r0 = blockIdx.y * 64;
  int c0 = blockIdx.x * 64;
  const float* I = in + (long)b * inBatch;
  unsigned short* O = out + (long)b * outBatch;
  int t = threadIdx.x;
  int cl = (t & 15) * 4;
  int rl = t >> 4;
#pragma unroll
  for (int rr = 0; rr < 4; ++rr) {
    int r = rl + rr * 16;
    float4 v = *reinterpret_cast<const float4*>(&I[(long)(r0 + r) * inCols + c0 + cl]);
    lt[cl + 0][r] = f2bf(v.x);
    lt[cl + 1][r] = f2bf(v.y);
    lt[cl + 2][r] = f2bf(v.z);
    lt[cl + 3][r] = f2bf(v.w);
  }
  __syncthreads();
#pragma unroll
  for (int rr = 0; rr < 4; ++rr) {
    int c = rl + rr * 16;
    unsigned short v[4] = {lt[c][cl], lt[c][cl + 1], lt[c][cl + 2], lt[c][cl + 3]};
    *reinterpret_cast<uint2*>(&O[(long)(c0 + c) * inRows + r0 + cl]) =
        *reinterpret_cast<uint2*>(&v[0]);
  }
}

// ======== 256x256 bf16 MFMA GEMM, BK=64, 8 waves, 8-PHASE schedule (m201) ========
template <int MODE>
__global__ __launch_bounds__(512) void mfma_nt256(const unsigned short* __restrict__ Abase,
                                                  const unsigned short* __restrict__ Bbase,
                                                  const float* __restrict__ rowscale,
                                                  unsigned short* __restrict__ Wout,
                                                  float* __restrict__ Fout) {
  __shared__ unsigned short As[2][256 * 64];
  __shared__ unsigned short Bs[2][256 * 64];
  const int t = threadIdx.x;
  const int l = t & 63;
  const int w = t >> 6;          // 0..7
  const int wr = w >> 2;         // 0..1  (M: 2 x 128)
  const int wc = w & 3;          // 0..3  (N: 4 x 64)

  const int cpx = gridDim.x >> 3;
  const int orig = blockIdx.x;
  const int lw = (orig & 7) * cpx + (orig >> 3);
  const int TPB_SH = (MODE == 0) ? 2 : 3;
  const int b = lw >> TPB_SH;
  const int tile = lw & ((1 << TPB_SH) - 1);
  const int mBase = (tile >> 1) * 256;
  const int nBase = (tile & 1) * 256;

  const unsigned short* Ag = Abase + ((MODE == 0) ? 0L : (long)b * (1024 * 512)) + (long)mBase * 512;
  const unsigned short* Bg = Bbase + (long)b * (512 * 512) + (long)nBase * 512;

  f32x4 acc[8][4];
#pragma unroll
  for (int m = 0; m < 8; ++m)
#pragma unroll
    for (int n = 0; n < 4; ++n) acc[m][n] = (f32x4){0.f, 0.f, 0.f, 0.f};

  const int srcslot = (l & 7) ^ (l >> 3);
  const int so0 = ((l >> 4) ^ (l & 7)) * 8;
  const int so1 = ((4 + (l >> 4)) ^ (l & 7)) * 8;

#define STG_A(p, tt, pr)                                                       \
  gld_lds16(Ag + (long)((pr) * 64 + w * 8 + (l >> 3)) * 512 + (tt) * 64 + srcslot * 8, \
            &As[p][((pr) * 64 + w * 8) * 64]);
#define STG_B(p, tt, pr)                                                       \
  gld_lds16(Bg + (long)((pr) * 64 + w * 8 + (l >> 3)) * 512 + (tt) * 64 + srcslot * 8, \
            &Bs[p][((pr) * 64 + w * 8) * 64]);

#define PHASE(p, q, STAGE_STMT, VMSTMT)                                        \
  {                                                                            \
    bf16x8 a00 = *reinterpret_cast<const bf16x8*>(                             \
        &As[p][(wr * 128 + (2 * (q)) * 16 + (l & 15)) * 64 + so0]);            \
    bf16x8 a01 = *reinterpret_cast<const bf16x8*>(                             \
        &As[p][(wr * 128 + (2 * (q)) * 16 + (l & 15)) * 64 + so1]);            \
    bf16x8 a10 = *reinterpret_cast<const bf16x8*>(                             \
        &As[p][(wr * 128 + (2 * (q) + 1) * 16 + (l & 15)) * 64 + so0]);        \
    bf16x8 a11 = *reinterpret_cast<const bf16x8*>(                             \
        &As[p][(wr * 128 + (2 * (q) + 1) * 16 + (l & 15)) * 64 + so1]);        \
    if ((q) == 0) {                                                            \
      _Pragma("unroll") for (int n = 0; n < 4; ++n) {                          \
        bfr0[n] = *reinterpret_cast<const bf16x8*>(                            \
            &Bs[p][(wc * 64 + n * 16 + (l & 15)) * 64 + so0]);                 \
        bfr1[n] = *reinterpret_cast<const bf16x8*>(                            \
            &Bs[p][(wc * 64 + n * 16 + (l & 15)) * 64 + so1]);                 \
      }                                                                        \
    }                                                                          \
    STAGE_STMT;                                                                \
    SCHED0();                                                                  \
    __builtin_amdgcn_s_barrier();                                              \
    LGKM0();                                                                   \
    __builtin_amdgcn_s_setprio(1);                                             \
    _Pragma("unroll") for (int n = 0; n < 4; ++n) {                            \
      acc[2 * (q)][n] = MFMA16(a00, bfr0[n], acc[2 * (q)][n]);                 \
      acc[2 * (q)][n] = MFMA16(a01, bfr1[n], acc[2 * (q)][n]);                 \
      acc[2 * (q) + 1][n] = MFMA16(a10, bfr0[n], acc[2 * (q) + 1][n]);         \
      acc[2 * (q) + 1][n] = MFMA16(a11, bfr1[n], acc[2 * (q) + 1][n]);         \
    }                                                                          \
    __builtin_amdgcn_s_setprio(0);                                             \
    VMSTMT;                                                                    \
    NTBAR();                                                                   \
  }

  bf16x8 bfr0[4], bfr1[4];

  // prologue: buf0 <- tile0 (8 loads), buf1 <- B0,B1,Ha of tile1 (6 loads)
  STG_A(0, 0, 0); STG_A(0, 0, 1); STG_A(0, 0, 2); STG_A(0, 0, 3);
  STG_B(0, 0, 0); STG_B(0, 0, 1); STG_B(0, 0, 2); STG_B(0, 0, 3);
  STG_B(1, 1, 0); STG_B(1, 1, 1); STG_B(1, 1, 2); STG_B(1, 1, 3);
  STG_A(1, 1, 0); STG_A(1, 1, 2);
  VMW(6);
  NTBAR();

  for (int it = 0; it < 4; ++it) {
    const int t1 = 2 * it + 1;
    const int t2 = (2 * it + 2 < 8) ? 2 * it + 2 : 7;
    const int t3 = (2 * it + 3 < 8) ? 2 * it + 3 : 7;
    PHASE(0, 0, { STG_A(1, t1, 1); STG_A(1, t1, 3); }, );
    PHASE(0, 1, { STG_B(0, t2, 0); STG_B(0, t2, 1); }, VMW(10));
    PHASE(0, 2, { STG_B(0, t2, 2); STG_B(0, t2, 3); }, );
    PHASE(0, 3, { STG_A(0, t2, 0); STG_A(0, t2, 2); }, VMW(8));
    PHASE(1, 0, { STG_A(0, t2, 1); STG_A(0, t2, 3); }, );
    PHASE(1, 1, { STG_B(1, t3, 0); STG_B(1, t3, 1); }, VMW(10));
    PHASE(1, 2, { STG_B(1, t3, 2); STG_B(1, t3, 3); }, );
    PHASE(1, 3, { STG_A(1, t3, 0); STG_A(1, t3, 2); }, VMW(8));
  }
#undef PHASE
#undef STG_A
#undef STG_B

  if (MODE == 0) {
    unsigned short* W = Wout + (long)b * (512 * 512);
#pragma unroll
    for (int n = 0; n < 4; ++n) {
      int j = nBase + wc * 64 + n * 16 + (l & 15);
      float rs = rowscale[b * 512 + j];
#pragma unroll
      for (int m = 0; m < 8; ++m) {
        int c0 = mBase + wr * 128 + m * 16 + (l >> 4) * 4;
        unsigned short p[4];
#pragma unroll
        for (int reg = 0; reg < 4; ++reg) p[reg] = f2bf(acc[m][n][reg] * rs);
        *reinterpret_cast<uint2*>(&W[(long)j * 512 + c0]) = *reinterpret_cast<uint2*>(p);
      }
    }
  } else {
    float* O = Fout + (long)b * (512 * 1024);
#pragma unroll
    for (int n = 0; n < 4; ++n) {
      int j = nBase + wc * 64 + n * 16 + (l & 15);
      float ab = rowscale[b * 512 + j];
#pragma unroll
      for (int m = 0; m < 8; ++m) {
        int n0 = mBase + wr * 128 + m * 16 + (l >> 4) * 4;
        *reinterpret_cast<float4*>(&O[(long)j * 1024 + n0]) =
            make_float4(acc[m][n][0] + ab, acc[m][n][1] + ab,
                        acc[m][n][2] + ab, acc[m][n][3] + ab);
      }
    }
  }
}

extern "C" void kernel_launch(void* const* d_in, const int* in_sizes, int n_in,
                              void* d_out, int out_size, void* d_ws, size_t ws_size,
                              hipStream_t stream) {
  const float* x  = (const float*)d_in[0];
  const float* Qm = (const float*)d_in[1];
  const float* Km = (const float*)d_in[2];
  const float* vw = (const float*)d_in[3];
  const float* vb = (const float*)d_in[4];
  float* out = (float*)d_out;

  float* ws = (float*)d_ws;
  unsigned short* qkh  = (unsigned short*)ws;                         // 4,194,304 ush
  unsigned short* qkl  = qkh + 4194304;                               // 4,194,304 ush
  unsigned short* st   = (unsigned short*)(ws + 4194304);             // spans 8,388,608 f
  unsigned short* weff = (unsigned short*)(ws + 4194304 + 8388608);   // spans 8,388,608 f
  unsigned short* xbT  = (unsigned short*)(ws + 4194304 + 16777216);  // spans 16,777,216 f
  unsigned short* vwT  = (unsigned short*)(ws + 4194304 + 33554432);  // spans 131,072 f
  unsigned short* qkTh = (unsigned short*)(ws + 4194304 + 33554432 + 131072);  // 65,536 f
  unsigned short* qkTl = qkTh + 131072;                               // 65,536 f
  float* rsum    = ws + 4194304 + 33554432 + 131072 + 131072;         // 32,768 f
  float* attbias = rsum + 32768;                                      // 32,768 f

  // T2: vwT[c][i] = bf16(vw[i][c])
  transpose_conv<<<dim3(8, 8, 1), 256, 0, stream>>>(vw, vwT, 512, 512, 0L, 0L);
  // T3: split-transposed [Qm|Km] -> qkTh/qkTl [128][1024]
  qkm_split<<<dim3(16, 2), 256, 0, stream>>>(Qm, Km, qkTh, qkTl);
  // K1: qkh/qkl = split(x @ [Qm|Km]) + fused xbT transpose (conflict-free Tt path)
  k1_mfma<<<512, 256, 0, stream>>>(x, qkTh, qkTl, qkh, qkl, xbT);
  // K2a: st[b,j,i] = exp(sigmoid(q_i . k_j)), gld_lds staging of qkh/qkl
  k2a_mfma<<<1024, 256, 0, stream>>>(qkh, qkl, st);
  // K2b: rsum, attbias
  k2b_rsum<<<8192, 256, 0, stream>>>(st, vb, rsum, attbias);
  // K3: weff = diag(rsum) . st . Vw   (A=vwT, B=st), 4 tiles/b
  mfma_nt256<0><<<256, 512, 0, stream>>>(vwT, st, rsum, weff, nullptr);
  // K4: out = weff . xf + attbias     (A=xbT, B=weff), 8 tiles/b
  mfma_nt256<1><<<512, 512, 0, stream>>>(xbT, weff, attbias, nullptr, out);
}

// Round 11
// 190.432 us; speedup vs baseline: 1.2447x; 1.0571x over previous
//
#include <hip/hip_runtime.h>

#define BK 32

typedef __attribute__((ext_vector_type(8))) short bf16x8;
typedef __attribute__((ext_vector_type(4))) float f32x4;

__device__ __forceinline__ unsigned short f2bf(float f) {
  unsigned u = __builtin_bit_cast(unsigned, f);
  unsigned r = (u + 0x7FFFu + ((u >> 16) & 1u)) >> 16;
  return (unsigned short)r;
}
__device__ __forceinline__ float bf2f(unsigned short h) {
  return __builtin_bit_cast(float, (unsigned)h << 16);
}
__device__ __forceinline__ unsigned pack2(unsigned short a, unsigned short b) {
  return (unsigned)a | ((unsigned)b << 16);
}

__device__ __forceinline__ void gld_lds16(const void* g, void* l) {
  __builtin_amdgcn_global_load_lds(
      (const __attribute__((address_space(1))) unsigned int*)g,
      (__attribute__((address_space(3))) unsigned int*)l, 16, 0, 0);
}

#define SCHED0() __builtin_amdgcn_sched_barrier(0)
#define NTBAR() do { SCHED0(); __builtin_amdgcn_s_barrier(); SCHED0(); } while (0)
#define VMW(N) do { asm volatile("s_waitcnt vmcnt(" #N ")" ::: "memory"); SCHED0(); } while (0)
#define LGKM0() do { asm volatile("s_waitcnt lgkmcnt(0)" ::: "memory"); SCHED0(); } while (0)
#define MFMA16(a, b, c) __builtin_amdgcn_mfma_f32_16x16x32_bf16(a, b, c, 0, 0, 0)

// split 8 fp32 -> hi/lo bf16, store as uint4 pair (ds_write_b128)
__device__ __forceinline__ void split8_store(float4 v0, float4 v1,
                                             unsigned short* Hdst,
                                             unsigned short* Ldst) {
  float f[8] = {v0.x, v0.y, v0.z, v0.w, v1.x, v1.y, v1.z, v1.w};
  unsigned short hh[8], ll[8];
#pragma unroll
  for (int i = 0; i < 8; ++i) {
    hh[i] = f2bf(f[i]);
    ll[i] = f2bf(f[i] - bf2f(hh[i]));
  }
  *reinterpret_cast<uint4*>(Hdst) = make_uint4(pack2(hh[0], hh[1]), pack2(hh[2], hh[3]),
                                               pack2(hh[4], hh[5]), pack2(hh[6], hh[7]));
  *reinterpret_cast<uint4*>(Ldst) = make_uint4(pack2(ll[0], ll[1]), pack2(ll[2], ll[3]),
                                               pack2(ll[4], ll[5]), pack2(ll[6], ll[7]));
}

// split + additionally scatter hi-bf16 into the transpose buffer Tt[k][c-swizzled]
__device__ __forceinline__ void split8_store_tt(float4 v0, float4 v1,
                                                unsigned short* Hdst,
                                                unsigned short* Ldst,
                                                unsigned short* Ttb,
                                                int kslot, int c) {
  float f[8] = {v0.x, v0.y, v0.z, v0.w, v1.x, v1.y, v1.z, v1.w};
  unsigned short hh[8], ll[8];
#pragma unroll
  for (int i = 0; i < 8; ++i) {
    hh[i] = f2bf(f[i]);
    ll[i] = f2bf(f[i] - bf2f(hh[i]));
  }
  *reinterpret_cast<uint4*>(Hdst) = make_uint4(pack2(hh[0], hh[1]), pack2(hh[2], hh[3]),
                                               pack2(hh[4], hh[5]), pack2(hh[6], hh[7]));
  *reinterpret_cast<uint4*>(Ldst) = make_uint4(pack2(ll[0], ll[1]), pack2(ll[2], ll[3]),
                                               pack2(ll[4], ll[5]), pack2(ll[6], ll[7]));
#pragma unroll
  for (int i = 0; i < 8; ++i) {
    int g = ((c >> 3) ^ i ^ kslot) & 7;  // (c>>3) ^ (k&7) ^ (k>>3), k = kslot*8+i
    Ttb[(kslot * 8 + i) * 72 + g * 8 + (c & 7)] = hh[i];
  }
}

// -------- QB prep: Th/Tl[d][k] = split-bf16 of [Qm | Km] column d --------
__global__ __launch_bounds__(256) void qkm_split(const float* __restrict__ Qm,
                                                 const float* __restrict__ Km,
                                                 unsigned short* __restrict__ Th,
                                                 unsigned short* __restrict__ Tl) {
  __shared__ float lt[64][65];
  int k0 = blockIdx.x * 64;
  int half = blockIdx.y;
  const float* M = half ? Km : Qm;
  int t = threadIdx.x;
  int cl = (t & 15) * 4;
  int rl = t >> 4;
#pragma unroll
  for (int rr = 0; rr < 4; ++rr) {
    int r = rl + rr * 16;
    float4 v = *reinterpret_cast<const float4*>(&M[(long)(k0 + r) * 64 + cl]);
    lt[cl + 0][r] = v.x;
    lt[cl + 1][r] = v.y;
    lt[cl + 2][r] = v.z;
    lt[cl + 3][r] = v.w;
  }
  __syncthreads();
#pragma unroll
  for (int rr = 0; rr < 4; ++rr) {
    int c = rl + rr * 16;
    unsigned short h[4], lo[4];
#pragma unroll
    for (int i = 0; i < 4; ++i) {
      float f = lt[c][cl + i];
      h[i] = f2bf(f);
      lo[i] = f2bf(f - bf2f(h[i]));
    }
    *reinterpret_cast<uint2*>(&Th[(long)(half * 64 + c) * 1024 + k0 + cl]) =
        make_uint2(pack2(h[0], h[1]), pack2(h[2], h[3]));
    *reinterpret_cast<uint2*>(&Tl[(long)(half * 64 + c) * 1024 + k0 + cl]) =
        make_uint2(pack2(lo[0], lo[1]), pack2(lo[2], lo[3]));
  }
}

// -------- K1: qk split-bf16 out + fused x-transpose (xbT) --------------------
// Counted-vmcnt raw-barrier pipeline. Per K-tile (BK=32), vmem issue order:
//   store xbT (1) | x-load t+2 (2) | BAR | gld_lds D(t+2) (4) | VMW(7) | BAR
// VMW(7) (in-order vmcnt retirement) == "previous iteration's 7 ops done":
// D(t+1) landed, old store acked — each covered by a full iteration.
__global__ __launch_bounds__(256) void k1_mfma(const float* __restrict__ x,
                                               const unsigned short* __restrict__ Th,
                                               const unsigned short* __restrict__ Tl,
                                               unsigned short* __restrict__ qkh,
                                               unsigned short* __restrict__ qkl,
                                               unsigned short* __restrict__ xbT) {
  __shared__ unsigned short Dh[2][128 * 32];
  __shared__ unsigned short Dl[2][128 * 32];
  __shared__ unsigned short Xh[2][64 * 32];
  __shared__ unsigned short Xl[2][64 * 32];
  __shared__ unsigned short Tt[2][32 * 72];
  const int t = threadIdx.x;
  const int l = t & 63;
  const int w = t >> 6;
  const int wr = w >> 1, wc = w & 1;
  const long mBase = (long)blockIdx.x * 64;
  const int b = blockIdx.x >> 3;
  const int cBase = (blockIdx.x & 7) * 64;

  f32x4 acc[4][2];
#pragma unroll
  for (int m = 0; m < 4; ++m)
#pragma unroll
    for (int n = 0; n < 2; ++n) acc[m][n] = (f32x4){0.f, 0.f, 0.f, 0.f};

  const int xrow_l = t >> 2;
  const int kslot = t & 3;
  const int xsl = kslot ^ ((t >> 3) & 3);
  const int srcslot = (l & 3) ^ ((l >> 3) & 3);
  const int frag_off = (l & 15) * 32 + ((((l >> 4) ^ (l >> 1)) & 3) * 8);
  const float* xrow = x + (mBase + xrow_l) * 1024;

  // x-load for K-tile tt (32 k): 2 float4 per thread
#define K1_LOADX(r0, r1, tt)                                                  \
  {                                                                           \
    r0 = *reinterpret_cast<const float4*>(&xrow[(tt) * 32 + kslot * 8]);      \
    r1 = *reinterpret_cast<const float4*>(&xrow[(tt) * 32 + kslot * 8 + 4]);  \
  }

  // D staging for K-tile tt into buffer p: 4 gld_lds per thread
#define K1_STAGE_D(tt, p)                                                     \
  {                                                                           \
    _Pragma("unroll") for (int c = 0; c < 2; ++c) {                           \
      int ch = c * 4 + w;                                                     \
      int row = ch * 16 + (l >> 2);                                           \
      gld_lds16(Th + (long)row * 1024 + (tt) * 32 + srcslot * 8, &Dh[p][ch * 512]); \
      gld_lds16(Tl + (long)row * 1024 + (tt) * 32 + srcslot * 8, &Dl[p][ch * 512]); \
    }                                                                         \
  }

#define K1_COMPUTE(p)                                                         \
  {                                                                           \
    bf16x8 dh[4], dl[4], xh[2], xl[2];                                        \
    _Pragma("unroll") for (int m = 0; m < 4; ++m) {                           \
      dh[m] = *reinterpret_cast<const bf16x8*>(&Dh[p][(wr * 64 + m * 16) * 32 + frag_off]); \
      dl[m] = *reinterpret_cast<const bf16x8*>(&Dl[p][(wr * 64 + m * 16) * 32 + frag_off]); \
    }                                                                         \
    _Pragma("unroll") for (int n = 0; n < 2; ++n) {                           \
      xh[n] = *reinterpret_cast<const bf16x8*>(&Xh[p][(wc * 32 + n * 16) * 32 + frag_off]); \
      xl[n] = *reinterpret_cast<const bf16x8*>(&Xl[p][(wc * 32 + n * 16) * 32 + frag_off]); \
    }                                                                         \
    _Pragma("unroll") for (int m = 0; m < 4; ++m)                             \
        _Pragma("unroll") for (int n = 0; n < 2; ++n) {                       \
      acc[m][n] = MFMA16(dh[m], xh[n], acc[m][n]);                            \
      acc[m][n] = MFMA16(dh[m], xl[n], acc[m][n]);                            \
      acc[m][n] = MFMA16(dl[m], xh[n], acc[m][n]);                            \
    }                                                                         \
  }

  // read one b128 row-slice from Tt[p] and store coalesced 16B to xbT
#define K1_WRITEBACK(p, kk)                                                   \
  {                                                                           \
    int n2 = t >> 3;                                                          \
    int g2 = t & 7;                                                           \
    int gs = (g2 ^ (n2 & 7) ^ (n2 >> 3)) & 7;                                 \
    uint4 vv = *reinterpret_cast<const uint4*>(&Tt[p][n2 * 72 + gs * 8]);     \
    *reinterpret_cast<uint4*>(                                                \
        &xbT[(long)b * 524288 + (long)((kk) + n2) * 512 + cBase + g2 * 8]) = vv; \
  }

  float4 xa0, xa1, xb0, xb1;

  // prologue: x(0)->A(2), D(0)(4), x(1)->B(2), split A->buf0, D(1)(4), VMW(6)
  K1_LOADX(xa0, xa1, 0);
  K1_STAGE_D(0, 0);
  K1_LOADX(xb0, xb1, 1);
  split8_store_tt(xa0, xa1, &Xh[0][xrow_l * 32 + xsl * 8], &Xl[0][xrow_l * 32 + xsl * 8],
                  Tt[0], kslot, xrow_l);
  K1_STAGE_D(1, 1);
  VMW(6);
  LGKM0();
  NTBAR();

  for (int kt = 0; kt < 32; kt += 2) {
    // even body: tile kt, p=0; split(B=x(kt+1)) -> buf1; load x(kt+2) -> A
    {
      const int tn = (kt + 2 < 32) ? kt + 2 : 31;
      K1_COMPUTE(0);
      K1_WRITEBACK(0, kt * 32);
      K1_LOADX(xa0, xa1, tn);
      split8_store_tt(xb0, xb1, &Xh[1][xrow_l * 32 + xsl * 8], &Xl[1][xrow_l * 32 + xsl * 8],
                      Tt[1], kslot, xrow_l);
      LGKM0();
      NTBAR();
      K1_STAGE_D(tn, 0);
      VMW(7);
      NTBAR();
    }
    // odd body: tile kt+1, p=1; split(A=x(kt+2)) -> buf0; load x(kt+3) -> B
    {
      const int tn = (kt + 3 < 32) ? kt + 3 : 31;
      K1_COMPUTE(1);
      K1_WRITEBACK(1, (kt + 1) * 32);
      K1_LOADX(xb0, xb1, tn);
      split8_store_tt(xa0, xa1, &Xh[0][xrow_l * 32 + xsl * 8], &Xl[0][xrow_l * 32 + xsl * 8],
                      Tt[0], kslot, xrow_l);
      LGKM0();
      NTBAR();
      K1_STAGE_D(tn, 1);
      VMW(7);
      NTBAR();
    }
  }

#pragma unroll
  for (int m = 0; m < 4; ++m)
#pragma unroll
    for (int n = 0; n < 2; ++n) {
      int d0 = wr * 64 + m * 16 + (l >> 4) * 4;
      long xr = mBase + wc * 32 + n * 16 + (l & 15);
      unsigned short h4[4], l4[4];
#pragma unroll
      for (int reg = 0; reg < 4; ++reg) {
        float v = acc[m][n][reg];
        h4[reg] = f2bf(v);
        l4[reg] = f2bf(v - bf2f(h4[reg]));
      }
      *reinterpret_cast<uint2*>(&qkh[xr * 128 + d0]) =
          make_uint2(pack2(h4[0], h4[1]), pack2(h4[2], h4[3]));
      *reinterpret_cast<uint2*>(&qkl[xr * 128 + d0]) =
          make_uint2(pack2(l4[0], l4[1]), pack2(l4[2], l4[3]));
    }
#undef K1_LOADX
#undef K1_STAGE_D
#undef K1_COMPUTE
#undef K1_WRITEBACK
}

// -------- K2a: st[b,j,i] = exp(sigmoid(q_i . k_j)), split-bf16 MFMA -----------
// Stages pre-split qkh/qkl via global_load_lds (lane-linear dest, swizzled src).
__global__ __launch_bounds__(256) void k2a_mfma(const unsigned short* __restrict__ qkh,
                                                const unsigned short* __restrict__ qkl,
                                                unsigned short* __restrict__ st) {
  __shared__ unsigned short Ah[128 * 64];
  __shared__ unsigned short Al[128 * 64];
  __shared__ unsigned short Bh[128 * 64];
  __shared__ unsigned short Bl[128 * 64];
  const int t = threadIdx.x;
  const int l = t & 63;
  const int w = t >> 6;
  const int wr = w >> 1, wc = w & 1;

  const int cpx = gridDim.x >> 3;
  const int orig = blockIdx.x;
  const int lw = (orig & 7) * cpx + (orig >> 3);
  const int b = lw >> 4;
  const int tile = lw & 15;
  const int iBase = (tile >> 2) * 128;
  const int jBase = (tile & 3) * 128;
  const long bq = (long)b * 512;

  const int sg = (l & 7) ^ (l >> 3);
#pragma unroll
  for (int c4 = 0; c4 < 4; ++c4) {
    int rb = w * 32 + c4 * 8;
    long rowA = bq + iBase + rb + (l >> 3);
    long rowB = bq + jBase + rb + (l >> 3);
    gld_lds16(qkh + rowA * 128 + sg * 8, &Ah[rb * 64]);
    gld_lds16(qkl + rowA * 128 + sg * 8, &Al[rb * 64]);
    gld_lds16(qkh + rowB * 128 + 64 + sg * 8, &Bh[rb * 64]);
    gld_lds16(qkl + rowB * 128 + 64 + sg * 8, &Bl[rb * 64]);
  }
  __syncthreads();

  f32x4 acc[4][4];
#pragma unroll
  for (int m = 0; m < 4; ++m)
#pragma unroll
    for (int n = 0; n < 4; ++n) acc[m][n] = (f32x4){0.f, 0.f, 0.f, 0.f};

#pragma unroll
  for (int ks = 0; ks < 2; ++ks) {
    bf16x8 ah[4], al4[4], bh[4], bl4[4];
#pragma unroll
    for (int m = 0; m < 4; ++m) {
      int row = wr * 64 + m * 16 + (l & 15);
      int off = row * 64 + ((ks * 4 + (l >> 4)) ^ (row & 7)) * 8;
      ah[m] = *reinterpret_cast<const bf16x8*>(&Ah[off]);
      al4[m] = *reinterpret_cast<const bf16x8*>(&Al[off]);
    }
#pragma unroll
    for (int n = 0; n < 4; ++n) {
      int row = wc * 64 + n * 16 + (l & 15);
      int off = row * 64 + ((ks * 4 + (l >> 4)) ^ (row & 7)) * 8;
      bh[n] = *reinterpret_cast<const bf16x8*>(&Bh[off]);
      bl4[n] = *reinterpret_cast<const bf16x8*>(&Bl[off]);
    }
#pragma unroll
    for (int m = 0; m < 4; ++m)
#pragma unroll
      for (int n = 0; n < 4; ++n) {
        acc[m][n] = MFMA16(ah[m], bh[n], acc[m][n]);
        acc[m][n] = MFMA16(ah[m], bl4[n], acc[m][n]);
        acc[m][n] = MFMA16(al4[m], bh[n], acc[m][n]);
      }
  }

  unsigned short* sb = st + (long)b * 512 * 512;
#pragma unroll
  for (int m = 0; m < 4; ++m)
#pragma unroll
    for (int n = 0; n < 4; ++n) {
      int i0 = iBase + wr * 64 + m * 16 + (l >> 4) * 4;
      int j = jBase + wc * 64 + n * 16 + (l & 15);
      unsigned short p[4];
#pragma unroll
      for (int reg = 0; reg < 4; ++reg) {
        float sg2 = 1.0f / (1.0f + __expf(-acc[m][n][reg]));
        p[reg] = f2bf(__expf(sg2));
      }
      *reinterpret_cast<uint2*>(&sb[(long)j * 512 + i0]) = *reinterpret_cast<uint2*>(p);
    }
}

// -------- K2b: per-row (j) sums of st -> rsum = 1/sum, attbias = (st.bias)/sum ----
__global__ __launch_bounds__(256) void k2b_rsum(const unsigned short* __restrict__ st,
                                                const float* __restrict__ bias,
                                                float* __restrict__ rsum,
                                                float* __restrict__ attbias) {
  int jg = blockIdx.x * 4 + (threadIdx.x >> 6);
  int l = threadIdx.x & 63;
  const unsigned short* row = st + (long)jg * 512 + l * 8;
  ushort4 u0 = *reinterpret_cast<const ushort4*>(row);
  ushort4 u1 = *reinterpret_cast<const ushort4*>(row + 4);
  float4 b0 = *reinterpret_cast<const float4*>(&bias[l * 8]);
  float4 b1 = *reinterpret_cast<const float4*>(&bias[l * 8 + 4]);
  float f0 = bf2f(u0.x), f1 = bf2f(u0.y), f2 = bf2f(u0.z), f3 = bf2f(u0.w);
  float f4 = bf2f(u1.x), f5 = bf2f(u1.y), f6 = bf2f(u1.z), f7 = bf2f(u1.w);
  float sum = (f0 + f1) + (f2 + f3) + ((f4 + f5) + (f6 + f7));
  float sumb = f0 * b0.x + f1 * b0.y + f2 * b0.z + f3 * b0.w +
               f4 * b1.x + f5 * b1.y + f6 * b1.z + f7 * b1.w;
#pragma unroll
  for (int off = 32; off > 0; off >>= 1) {
    sum += __shfl_down(sum, off);
    sumb += __shfl_down(sumb, off);
  }
  if (l == 0) {
    float r = 1.0f / sum;
    rsum[jg] = r;
    attbias[jg] = sumb * r;
  }
}

// -------- transpose + fp32->bf16 convert: out[c][r] = bf16(in[r][c]) --------
__global__ __launch_bounds__(256) void transpose_conv(const float* __restrict__ in,
                                                      unsigned short* __restrict__ out,
                                                      int inRows, int inCols,
                                                      long inBatch, long outBatch) {
  __shared__ unsigned short lt[64][65];
  int b = blockIdx.z;
  int r0 = blockIdx.y * 64;
  int c0 = blockIdx.x * 64;
  const float* I = in + (long)b * inBatch;
  unsigned short* O = out + (long)b * outBatch;
  int t = threadIdx.x;
  int cl = (t & 15) * 4;
  int rl = t >> 4;
#pragma unroll
  for (int rr = 0; rr < 4; ++rr) {
    int r = rl + rr * 16;
    float4 v = *reinterpret_cast<const float4*>(&I[(long)(r0 + r) * inCols + c0 + cl]);
    lt[cl + 0][r] = f2bf(v.x);
    lt[cl + 1][r] = f2bf(v.y);
    lt[cl + 2][r] = f2bf(v.z);
    lt[cl + 3][r] = f2bf(v.w);
  }
  __syncthreads();
#pragma unroll
  for (int rr = 0; rr < 4; ++rr) {
    int c = rl + rr * 16;
    unsigned short v[4] = {lt[c][cl], lt[c][cl + 1], lt[c][cl + 2], lt[c][cl + 3]};
    *reinterpret_cast<uint2*>(&O[(long)(c0 + c) * inRows + r0 + cl]) =
        *reinterpret_cast<uint2*>(&v[0]);
  }
}

// ======== 256x256 bf16 MFMA GEMM, BK=64, 8 waves, 8-PHASE schedule (m201) ========
template <int MODE>
__global__ __launch_bounds__(512) void mfma_nt256(const unsigned short* __restrict__ Abase,
                                                  const unsigned short* __restrict__ Bbase,
                                                  const float* __restrict__ rowscale,
                                                  unsigned short* __restrict__ Wout,
                                                  float* __restrict__ Fout) {
  __shared__ unsigned short As[2][256 * 64];
  __shared__ unsigned short Bs[2][256 * 64];
  const int t = threadIdx.x;
  const int l = t & 63;
  const int w = t >> 6;          // 0..7
  const int wr = w >> 2;         // 0..1  (M: 2 x 128)
  const int wc = w & 3;          // 0..3  (N: 4 x 64)

  const int cpx = gridDim.x >> 3;
  const int orig = blockIdx.x;
  const int lw = (orig & 7) * cpx + (orig >> 3);
  const int TPB_SH = (MODE == 0) ? 2 : 3;
  const int b = lw >> TPB_SH;
  const int tile = lw & ((1 << TPB_SH) - 1);
  const int mBase = (tile >> 1) * 256;
  const int nBase = (tile & 1) * 256;

  const unsigned short* Ag = Abase + ((MODE == 0) ? 0L : (long)b * (1024 * 512)) + (long)mBase * 512;
  const unsigned short* Bg = Bbase + (long)b * (512 * 512) + (long)nBase * 512;

  f32x4 acc[8][4];
#pragma unroll
  for (int m = 0; m < 8; ++m)
#pragma unroll
    for (int n = 0; n < 4; ++n) acc[m][n] = (f32x4){0.f, 0.f, 0.f, 0.f};

  const int srcslot = (l & 7) ^ (l >> 3);
  const int so0 = ((l >> 4) ^ (l & 7)) * 8;
  const int so1 = ((4 + (l >> 4)) ^ (l & 7)) * 8;

#define STG_A(p, tt, pr)                                                       \
  gld_lds16(Ag + (long)((pr) * 64 + w * 8 + (l >> 3)) * 512 + (tt) * 64 + srcslot * 8, \
            &As[p][((pr) * 64 + w * 8) * 64]);
#define STG_B(p, tt, pr)                                                       \
  gld_lds16(Bg + (long)((pr) * 64 + w * 8 + (l >> 3)) * 512 + (tt) * 64 + srcslot * 8, \
            &Bs[p][((pr) * 64 + w * 8) * 64]);

#define PHASE(p, q, STAGE_STMT, VMSTMT)                                        \
  {                                                                            \
    bf16x8 a00 = *reinterpret_cast<const bf16x8*>(                             \
        &As[p][(wr * 128 + (2 * (q)) * 16 + (l & 15)) * 64 + so0]);            \
    bf16x8 a01 = *reinterpret_cast<const bf16x8*>(                             \
        &As[p][(wr * 128 + (2 * (q)) * 16 + (l & 15)) * 64 + so1]);            \
    bf16x8 a10 = *reinterpret_cast<const bf16x8*>(                             \
        &As[p][(wr * 128 + (2 * (q) + 1) * 16 + (l & 15)) * 64 + so0]);        \
    bf16x8 a11 = *reinterpret_cast<const bf16x8*>(                             \
        &As[p][(wr * 128 + (2 * (q) + 1) * 16 + (l & 15)) * 64 + so1]);        \
    if ((q) == 0) {                                                            \
      _Pragma("unroll") for (int n = 0; n < 4; ++n) {                          \
        bfr0[n] = *reinterpret_cast<const bf16x8*>(                            \
            &Bs[p][(wc * 64 + n * 16 + (l & 15)) * 64 + so0]);                 \
        bfr1[n] = *reinterpret_cast<const bf16x8*>(                            \
            &Bs[p][(wc * 64 + n * 16 + (l & 15)) * 64 + so1]);                 \
      }                                                                        \
    }                                                                          \
    STAGE_STMT;                                                                \
    SCHED0();                                                                  \
    __builtin_amdgcn_s_barrier();                                              \
    LGKM0();                                                                   \
    __builtin_amdgcn_s_setprio(1);                                             \
    _Pragma("unroll") for (int n = 0; n < 4; ++n) {                            \
      acc[2 * (q)][n] = MFMA16(a00, bfr0[n], acc[2 * (q)][n]);                 \
      acc[2 * (q)][n] = MFMA16(a01, bfr1[n], acc[2 * (q)][n]);                 \
      acc[2 * (q) + 1][n] = MFMA16(a10, bfr0[n], acc[2 * (q) + 1][n]);         \
      acc[2 * (q) + 1][n] = MFMA16(a11, bfr1[n], acc[2 * (q) + 1][n]);         \
    }                                                                          \
    __builtin_amdgcn_s_setprio(0);                                             \
    VMSTMT;                                                                    \
    NTBAR();                                                                   \
  }

  bf16x8 bfr0[4], bfr1[4];

  // prologue: buf0 <- tile0 (8 loads), buf1 <- B0,B1,Ha of tile1 (6 loads)
  STG_A(0, 0, 0); STG_A(0, 0, 1); STG_A(0, 0, 2); STG_A(0, 0, 3);
  STG_B(0, 0, 0); STG_B(0, 0, 1); STG_B(0, 0, 2); STG_B(0, 0, 3);
  STG_B(1, 1, 0); STG_B(1, 1, 1); STG_B(1, 1, 2); STG_B(1, 1, 3);
  STG_A(1, 1, 0); STG_A(1, 1, 2);
  VMW(6);
  NTBAR();

  for (int it = 0; it < 4; ++it) {
    const int t1 = 2 * it + 1;
    const int t2 = (2 * it + 2 < 8) ? 2 * it + 2 : 7;
    const int t3 = (2 * it + 3 < 8) ? 2 * it + 3 : 7;
    PHASE(0, 0, { STG_A(1, t1, 1); STG_A(1, t1, 3); }, );
    PHASE(0, 1, { STG_B(0, t2, 0); STG_B(0, t2, 1); }, VMW(10));
    PHASE(0, 2, { STG_B(0, t2, 2); STG_B(0, t2, 3); }, );
    PHASE(0, 3, { STG_A(0, t2, 0); STG_A(0, t2, 2); }, VMW(8));
    PHASE(1, 0, { STG_A(0, t2, 1); STG_A(0, t2, 3); }, );
    PHASE(1, 1, { STG_B(1, t3, 0); STG_B(1, t3, 1); }, VMW(10));
    PHASE(1, 2, { STG_B(1, t3, 2); STG_B(1, t3, 3); }, );
    PHASE(1, 3, { STG_A(1, t3, 0); STG_A(1, t3, 2); }, VMW(8));
  }
#undef PHASE
#undef STG_A
#undef STG_B

  if (MODE == 0) {
    unsigned short* W = Wout + (long)b * (512 * 512);
#pragma unroll
    for (int n = 0; n < 4; ++n) {
      int j = nBase + wc * 64 + n * 16 + (l & 15);
      float rs = rowscale[b * 512 + j];
#pragma unroll
      for (int m = 0; m < 8; ++m) {
        int c0 = mBase + wr * 128 + m * 16 + (l >> 4) * 4;
        unsigned short p[4];
#pragma unroll
        for (int reg = 0; reg < 4; ++reg) p[reg] = f2bf(acc[m][n][reg] * rs);
        *reinterpret_cast<uint2*>(&W[(long)j * 512 + c0]) = *reinterpret_cast<uint2*>(p);
      }
    }
  } else {
    float* O = Fout + (long)b * (512 * 1024);
#pragma unroll
    for (int n = 0; n < 4; ++n) {
      int j = nBase + wc * 64 + n * 16 + (l & 15);
      float ab = rowscale[b * 512 + j];
#pragma unroll
      for (int m = 0; m < 8; ++m) {
        int n0 = mBase + wr * 128 + m * 16 + (l >> 4) * 4;
        *reinterpret_cast<float4*>(&O[(long)j * 1024 + n0]) =
            make_float4(acc[m][n][0] + ab, acc[m][n][1] + ab,
                        acc[m][n][2] + ab, acc[m][n][3] + ab);
      }
    }
  }
}

extern "C" void kernel_launch(void* const* d_in, const int* in_sizes, int n_in,
                              void* d_out, int out_size, void* d_ws, size_t ws_size,
                              hipStream_t stream) {
  const float* x  = (const float*)d_in[0];
  const float* Qm = (const float*)d_in[1];
  const float* Km = (const float*)d_in[2];
  const float* vw = (const float*)d_in[3];
  const float* vb = (const float*)d_in[4];
  float* out = (float*)d_out;

  float* ws = (float*)d_ws;
  unsigned short* qkh  = (unsigned short*)ws;                         // 4,194,304 ush
  unsigned short* qkl  = qkh + 4194304;                               // 4,194,304 ush
  unsigned short* st   = (unsigned short*)(ws + 4194304);             // spans 8,388,608 f
  unsigned short* weff = (unsigned short*)(ws + 4194304 + 8388608);   // spans 8,388,608 f
  unsigned short* xbT  = (unsigned short*)(ws + 4194304 + 16777216);  // spans 16,777,216 f
  unsigned short* vwT  = (unsigned short*)(ws + 4194304 + 33554432);  // spans 131,072 f
  unsigned short* qkTh = (unsigned short*)(ws + 4194304 + 33554432 + 131072);  // 65,536 f
  unsigned short* qkTl = qkTh + 131072;                               // 65,536 f
  float* rsum    = ws + 4194304 + 33554432 + 131072 + 131072;         // 32,768 f
  float* attbias = rsum + 32768;                                      // 32,768 f

  // T2: vwT[c][i] = bf16(vw[i][c])
  transpose_conv<<<dim3(8, 8, 1), 256, 0, stream>>>(vw, vwT, 512, 512, 0L, 0L);
  // T3: split-transposed [Qm|Km] -> qkTh/qkTl [128][1024]
  qkm_split<<<dim3(16, 2), 256, 0, stream>>>(Qm, Km, qkTh, qkTl);
  // K1: qkh/qkl = split(x @ [Qm|Km]) + fused xbT transpose (counted-vmcnt pipeline)
  k1_mfma<<<512, 256, 0, stream>>>(x, qkTh, qkTl, qkh, qkl, xbT);
  // K2a: st[b,j,i] = exp(sigmoid(q_i . k_j)), gld_lds staging of qkh/qkl
  k2a_mfma<<<1024, 256, 0, stream>>>(qkh, qkl, st);
  // K2b: rsum, attbias
  k2b_rsum<<<8192, 256, 0, stream>>>(st, vb, rsum, attbias);
  // K3: weff = diag(rsum) . st . Vw   (A=vwT, B=st), 4 tiles/b
  mfma_nt256<0><<<256, 512, 0, stream>>>(vwT, st, rsum, weff, nullptr);
  // K4: out = weff . xf + attbias     (A=xbT, B=weff), 8 tiles/b
  mfma_nt256<1><<<512, 512, 0, stream>>>(xbT, weff, attbias, nullptr, out);
}